// Round 9
// baseline (577.389 us; speedup 1.0000x reference)
//
#include <hip/hip_runtime.h>
#include <math.h>

__device__ const int d_PERM[9] = {0,2,6,3,7,1,5,8,4};
__device__ const int d_DEG[9]  = {0,1,1,1,2,2,2,2,2};

__device__ __forceinline__ float silu_f(float x){ return x / (1.0f + __expf(-x)); }

// flag: 0 = int32 words, 1 = u8 bytes, 2 = float32 words, 3 = int64 (low word)
__device__ __forceinline__ int mask_at(const void* mp, int flag, int e){
  if (flag==1) return ((const unsigned char*)mp)[e] != 0;
  if (flag==3) return ((const unsigned int*)mp)[2*e] != 0u;
  return ((const unsigned int*)mp)[e] != 0u;
}

__global__ void k_detect(const unsigned int* __restrict__ w, int* __restrict__ flag){
  __shared__ int notI, notF, anyOdd, anyEven;
  if (threadIdx.x==0){ notI=0; notF=0; anyOdd=0; anyEven=0; }
  __syncthreads();
  int li=0, lf=0, lo=0, le=0;
  for (int i = threadIdx.x; i < 1024; i += 256){
    unsigned int v = w[i];
    if (v != 0u && v != 1u) li = 1;
    if (v != 0u && v != 0x3F800000u) lf = 1;
    if (v != 0u){ if (i & 1) lo = 1; else le = 1; }
  }
  if (li) atomicOr(&notI,1);
  if (lf) atomicOr(&notF,1);
  if (lo) atomicOr(&anyOdd,1);
  if (le) atomicOr(&anyEven,1);
  __syncthreads();
  if (threadIdx.x==0){
    int f;
    if (!notI) f = (anyOdd || !anyEven) ? 0 : 3;
    else       f = (!notF) ? 2 : 1;
    *flag = f;
  }
}

// ---------------- H = x @ w_in[DEG] (+b_in at j==0), (N,9,128) ----------------
__global__ __launch_bounds__(128) void k_h(const float* __restrict__ x,
    const float* __restrict__ w_in, const float* __restrict__ b_in,
    float* __restrict__ H){
  __shared__ float xl[16][260];
  int i = blockIdx.y; int n0 = blockIdx.x*16;
  int deg = d_DEG[i];
  for (int idx = threadIdx.x; idx < 16*256; idx += 128){
    int r = idx >> 8, c = idx & 255;
    xl[r][c] = x[((size_t)(n0+r)*9 + i)*256 + c];
  }
  __syncthreads();
  int o = threadIdx.x;
  float acc[16];
  #pragma unroll
  for (int r=0;r<16;r++) acc[r]=0.f;
  const float* w = w_in + (size_t)deg*32768 + o;
  for (int c=0;c<256;c+=4){
    float w0=w[(size_t)c*128], w1=w[(size_t)(c+1)*128], w2=w[(size_t)(c+2)*128], w3=w[(size_t)(c+3)*128];
    #pragma unroll
    for (int r=0;r<16;r++){
      float4 xv4 = *(const float4*)&xl[r][c];
      acc[r] += xv4.x*w0 + xv4.y*w1 + xv4.z*w2 + xv4.w*w3;
    }
  }
  float bb = (i==0)? b_in[o] : 0.f;
  #pragma unroll
  for (int r=0;r<16;r++) H[((size_t)(n0+r)*9+i)*128+o] = acc[r]+bb;
}

// ---------------- XE (E,16) ----------------
__global__ __launch_bounds__(256) void k_xe(const float* __restrict__ attn,
    const float* __restrict__ fdw, const float* __restrict__ fdb,
    const float* __restrict__ few, const float* __restrict__ feb,
    const float* __restrict__ es, const float* __restrict__ et,
    const int* __restrict__ an, const int* __restrict__ esrc,
    float* __restrict__ XE){
  int e = blockIdx.x*256 + threadIdx.x;
  float aw[32];
  #pragma unroll
  for (int k=0;k<32;k+=4){
    float4 v = *(const float4*)&attn[(size_t)e*32+k];
    aw[k]=v.x; aw[k+1]=v.y; aw[k+2]=v.z; aw[k+3]=v.w;
  }
  int src = esrc[e]; int tgt = e>>3;
  int za = an[src], zb = an[tgt];
  float v0[16];
  #pragma unroll
  for (int j=0;j<16;j++){
    float s = fdb[j] + es[(size_t)za*16+j] + et[(size_t)zb*16+j];
    #pragma unroll
    for (int k=0;k<32;k++) s += aw[k]*fdw[k*16+j];
    v0[j] = silu_f(s);
  }
  #pragma unroll
  for (int j=0;j<16;j++){
    float s = feb[j];
    #pragma unroll
    for (int k=0;k<16;k++) s += v0[k]*few[k*16+j];
    XE[(size_t)e*16+j] = silu_f(s);
  }
}

// ================= rotate + gates (per edge, dense) =================
__global__ __launch_bounds__(256) void k_rotgate(
    const float* __restrict__ Hg, const float* __restrict__ XEg,
    const int* __restrict__ esrc, const float* __restrict__ wig,
    const float* __restrict__ d0w,  const float* __restrict__ d0b,
    const float* __restrict__ m1dw, const float* __restrict__ m1db,
    const float* __restrict__ m2dw, const float* __restrict__ m2db,
    float* __restrict__ XS, float* __restrict__ XT, float* __restrict__ G,
    int e0)
{
  __shared__ float xe16[16];
  int el = blockIdx.x;
  int e = e0 + el;
  int tid = threadIdx.x;
  int n = e >> 3, src = esrc[e];
  if (tid < 16) xe16[tid] = XEg[(size_t)e*16 + tid];
  for (int idx = tid; idx < 1152; idx += 256){
    int p = idx >> 7, c = idx & 127;
    int ch = d_PERM[p];
    const float* wr = wig + (size_t)e*81 + ch*9;
    const float* hs = Hg + (size_t)src*1152 + c;
    const float* ht = Hg + (size_t)n*1152 + c;
    float s1 = 0.f, s2 = 0.f;
    #pragma unroll
    for (int j = 0; j < 9; j++){
      float wv = wr[j];
      s1 += wv * hs[j*128];
      s2 += wv * ht[j*128];
    }
    XS[(size_t)el*1152 + idx] = s1;
    XT[(size_t)el*1152 + idx] = s2;
  }
  __syncthreads();
  for (int col = tid; col < 1280; col += 256){
    int b = col / 640, r = col % 640;
    const float* w; float bias; int ldw, c2;
    if (r < 128){       w = d0w  + (size_t)b*2048; c2 = r;     ldw = 128; bias = d0b[b*128 + c2]; }
    else if (r < 384){  w = m1dw + (size_t)b*4096; c2 = r-128; ldw = 256; bias = m1db[b*256 + c2]; }
    else {              w = m2dw + (size_t)b*4096; c2 = r-384; ldw = 256; bias = m2db[b*256 + c2]; }
    float s = bias;
    #pragma unroll
    for (int kk = 0; kk < 16; kk++) s += xe16[kk] * w[kk*ldw + c2];
    G[(size_t)el*1280 + col] = silu_f(s);
  }
}

// ================= stage-1 tiled GEMM (all regions in one launch) =================
// tiles: [0,128) m0 | [128,640) m1 (q=i>>7) | [640,1152) m2 (q=i>>7)
__global__ __launch_bounds__(256) void k_gs1(
    const float* __restrict__ XS, const float* __restrict__ XT,
    const float* __restrict__ G,
    const float* __restrict__ m0w1,
    const float* __restrict__ m1w1r, const float* __restrict__ m1w1i,
    const float* __restrict__ m2w1r, const float* __restrict__ m2w1i,
    float* __restrict__ Pg)
{
  __shared__ float As[16][68];
  __shared__ float Bs[16][68];
  int b = blockIdx.x;
  int t = threadIdx.x;
  const float* Ax; const float* Bw;
  int K, bm, hbase, obase, goff, rsh, aoff, tstride;
  if (b < 128){
    int mt = b>>2, nt = b&3;
    int path = nt>>1;
    Ax = path ? XT : XS;
    Bw = m0w1 + (size_t)path*49152 + (nt&1)*64;
    K = 384; bm = mt*64; hbase = (nt&1)*64;
    obase = path*128; goff = path ? 640 : 0;
    rsh = 0; aoff = 0; tstride = 0;
  } else if (b < 640){
    int i = b-128; int q = i>>7; int rr = i&127; int mt = rr>>1, nt = rr&1;
    Ax = (q>=2) ? XT : XS;
    Bw = ((q&1) ? m1w1i : m1w1r) + (size_t)((q>=2)?1:0)*32768 + nt*64;
    K = 256; bm = mt*64; hbase = nt*64;
    obase = 256 + q*256; goff = 128 + (q&1)*128 + (q>>1)*640;
    rsh = 1; aoff = 384; tstride = 256;
  } else {
    int i = b-640; int q = i>>7; int rr = i&127; int mt = rr>>1, nt = rr&1;
    Ax = (q>=2) ? XT : XS;
    Bw = ((q&1) ? m2w1i : m2w1r) + (size_t)((q>=2)?1:0)*16384 + nt*64;
    K = 128; bm = mt*64; hbase = nt*64;
    obase = 1280 + q*256; goff = 384 + (q&1)*128 + (q>>1)*640;
    rsh = 1; aoff = 896; tstride = 128;
  }
  int ar = t>>2, ak = (t&3)*4;
  int am = bm + ar;
  int ael = am >> rsh, atp = am & rsh;
  const float* aptr = Ax + (size_t)ael*1152 + aoff + atp*tstride + ak;
  int kb = t>>4, nbb = (t&15)*4;
  const float* bptr = Bw + (size_t)kb*128 + nbb;
  int tx = t&15, ty = t>>4;
  float acc[4][4];
  #pragma unroll
  for (int i2=0;i2<4;i2++){ acc[i2][0]=0.f; acc[i2][1]=0.f; acc[i2][2]=0.f; acc[i2][3]=0.f; }
  for (int k0=0;k0<K;k0+=16){
    float4 av = *(const float4*)(aptr + k0);
    float4 bv = *(const float4*)(bptr + (size_t)k0*128);
    As[ak+0][ar]=av.x; As[ak+1][ar]=av.y; As[ak+2][ar]=av.z; As[ak+3][ar]=av.w;
    *(float4*)&Bs[kb][nbb] = bv;
    __syncthreads();
    #pragma unroll
    for (int k=0;k<16;k++){
      float4 a4 = *(const float4*)&As[k][ty*4];
      float4 b4 = *(const float4*)&Bs[k][tx*4];
      acc[0][0]+=a4.x*b4.x; acc[0][1]+=a4.x*b4.y; acc[0][2]+=a4.x*b4.z; acc[0][3]+=a4.x*b4.w;
      acc[1][0]+=a4.y*b4.x; acc[1][1]+=a4.y*b4.y; acc[1][2]+=a4.y*b4.z; acc[1][3]+=a4.y*b4.w;
      acc[2][0]+=a4.z*b4.x; acc[2][1]+=a4.z*b4.y; acc[2][2]+=a4.z*b4.z; acc[2][3]+=a4.z*b4.w;
      acc[3][0]+=a4.w*b4.x; acc[3][1]+=a4.w*b4.y; acc[3][2]+=a4.w*b4.z; acc[3][3]+=a4.w*b4.w;
    }
    __syncthreads();
  }
  #pragma unroll
  for (int i2=0;i2<4;i2++){
    int m = bm + ty*4 + i2;
    int el = m >> rsh, tp = m & rsh;
    int h = hbase + tx*4;
    float4 gv = *(const float4*)&G[(size_t)el*1280 + goff + h];
    float4 v = make_float4(acc[i2][0]*gv.x, acc[i2][1]*gv.y, acc[i2][2]*gv.z, acc[i2][3]*gv.w);
    *(float4*)&Pg[(size_t)el*2304 + obase + tp*128 + h] = v;
  }
}

// ================= stage-2 tiled GEMM -> Y (orig channel order) =================
// tiles: [0,192) m0 | [192,448) m1 | [448,576) m2
__global__ __launch_bounds__(256) void k_gs2(
    const float* __restrict__ Pg,
    const float* __restrict__ m0w2,
    const float* __restrict__ m1w2r, const float* __restrict__ m1w2i,
    const float* __restrict__ m2w2r, const float* __restrict__ m2w2i,
    float* __restrict__ Y)
{
  __shared__ float As[16][68];
  __shared__ float Bs[16][68];
  int b = blockIdx.x;
  int t = threadIdx.x;
  int region, bm, ncolbase, K;
  if (b < 192){ region=0; int mt=b/6, nt=b-mt*6; bm=mt*64; ncolbase=nt*64; K=256; }
  else if (b < 448){ region=1; int i=b-192; int mt=i>>2, nt=i&3; bm=mt*64; ncolbase=nt*64; K=512; }
  else { region=2; int i=b-448; int mt=i>>1, nt=i&1; bm=mt*64; ncolbase=nt*64; K=512; }

  int ar = t>>2, ak = (t&3)*4;
  int am = bm + ar;
  int kb = t>>4, nbb = (t&15)*4;
  int tx = t&15, ty = t>>4;
  float acc[4][4];
  #pragma unroll
  for (int i2=0;i2<4;i2++){ acc[i2][0]=0.f; acc[i2][1]=0.f; acc[i2][2]=0.f; acc[i2][3]=0.f; }

  int ael, atp; float asgn_base;
  if (region==0){ ael = am; atp = 0; asgn_base = 1.f; }
  else { ael = am>>1; atp = am&1; asgn_base = atp ? 1.f : -1.f; }
  int segbase0 = (region==2) ? 1280 : 256;

  for (int k0=0;k0<K;k0+=16){
    // ---- A load ----
    float4 av;
    if (region==0){
      av = *(const float4*)(Pg + (size_t)ael*2304 + k0 + ak);
    } else {
      int ks = k0 + ak;
      int seg = ks>>7, kk = ks&127;
      int tsel = (seg&1) ? (1-atp) : atp;
      float sg = (seg&1) ? asgn_base : 1.f;
      av = *(const float4*)(Pg + (size_t)ael*2304 + segbase0 + seg*256 + tsel*128 + kk);
      av.x *= sg; av.y *= sg; av.z *= sg; av.w *= sg;
    }
    // ---- B load ----
    float4 bv;
    int ks2 = k0 + kb;
    if (region==0){
      bv = *(const float4*)(m0w2 + (size_t)(ks2>>7)*49152 + (size_t)(ks2&127)*384 + ncolbase + nbb);
    } else if (region==1){
      const float* base = ((ks2>>7)&1) ? m1w2i : m1w2r;
      bv = *(const float4*)(base + (size_t)(ks2>>8)*32768 + (size_t)(ks2&127)*256 + ncolbase + nbb);
    } else {
      const float* base = ((ks2>>7)&1) ? m2w2i : m2w2r;
      bv = *(const float4*)(base + (size_t)(ks2>>8)*16384 + (size_t)(ks2&127)*128 + ncolbase + nbb);
    }
    As[ak+0][ar]=av.x; As[ak+1][ar]=av.y; As[ak+2][ar]=av.z; As[ak+3][ar]=av.w;
    *(float4*)&Bs[kb][nbb] = bv;
    __syncthreads();
    #pragma unroll
    for (int k=0;k<16;k++){
      float4 a4 = *(const float4*)&As[k][ty*4];
      float4 b4 = *(const float4*)&Bs[k][tx*4];
      acc[0][0]+=a4.x*b4.x; acc[0][1]+=a4.x*b4.y; acc[0][2]+=a4.x*b4.z; acc[0][3]+=a4.x*b4.w;
      acc[1][0]+=a4.y*b4.x; acc[1][1]+=a4.y*b4.y; acc[1][2]+=a4.y*b4.z; acc[1][3]+=a4.y*b4.w;
      acc[2][0]+=a4.z*b4.x; acc[2][1]+=a4.z*b4.y; acc[2][2]+=a4.z*b4.z; acc[2][3]+=a4.z*b4.w;
      acc[3][0]+=a4.w*b4.x; acc[3][1]+=a4.w*b4.y; acc[3][2]+=a4.w*b4.z; acc[3][3]+=a4.w*b4.w;
    }
    __syncthreads();
  }
  #pragma unroll
  for (int i2=0;i2<4;i2++){
    int m = bm + ty*4 + i2;
    int el, tp;
    if (region==0){ el = m; tp = 0; } else { el = m>>1; tp = m&1; }
    int col = ncolbase + tx*4;
    int g = col >> 7, c = col & 127;
    int ch;
    if (region==0)      ch = (g==0) ? 0 : ((g==1) ? 2 : 6);
    else if (region==1) ch = tp ? (g ? 5 : 1) : (g ? 7 : 3);
    else                ch = tp ? 4 : 8;
    float4 v = make_float4(acc[i2][0],acc[i2][1],acc[i2][2],acc[i2][3]);
    *(float4*)&Y[(size_t)el*1152 + ch*128 + c] = v;
  }
}

// ================= grid (to_grid -> silu -> from_grid) + wigner^T -> R =================
__global__ __launch_bounds__(256) void k_grid2(const float* __restrict__ Y,
    const float* __restrict__ wig, const float* __restrict__ tg, const float* __restrict__ fg,
    const void* __restrict__ maskp, const int* __restrict__ flagp,
    float* __restrict__ R, int e0)
{
  __shared__ float Zb[2304];
  __shared__ float wl[81];
  int el = blockIdx.x;
  int e = e0 + el;
  if (mask_at(maskp, *flagp, e)) return;
  int tid = threadIdx.x;
  for (int i = tid; i < 81; i += 256) wl[i] = wig[(size_t)e*81 + i];
  int half = tid >> 7, c = tid & 127;
  float y[9];
  #pragma unroll
  for (int i = 0; i < 9; i++) y[i] = Y[(size_t)el*1152 + i*128 + c];
  float z[9];
  #pragma unroll
  for (int i = 0; i < 9; i++) z[i] = 0.f;
  int p0 = half*162, p1 = p0 + 162;
  #pragma unroll 2
  for (int p = p0; p < p1; p++){
    float gp = 0.f;
    #pragma unroll
    for (int i = 0; i < 9; i++) gp += tg[p*9 + i] * y[i];
    float s = silu_f(gp);
    #pragma unroll
    for (int i = 0; i < 9; i++) z[i] += fg[p*9 + i] * s;
  }
  #pragma unroll
  for (int i = 0; i < 9; i++) Zb[half*1152 + i*128 + c] = z[i];
  __syncthreads();
  for (int idx = tid; idx < 1152; idx += 256){
    int i2 = idx >> 7, c2 = idx & 127;
    float s = 0.f;
    #pragma unroll
    for (int j = 0; j < 9; j++)
      s += wl[j*9 + i2] * (Zb[j*128 + c2] + Zb[1152 + j*128 + c2]);
    R[(size_t)el*1152 + idx] = s;
  }
}

// ================= masked reduce + w_out projection (R chunk-local from atom n0) =========
__global__ __launch_bounds__(256) void k_redout(const float* __restrict__ R,
    const void* __restrict__ maskp, const int* __restrict__ flagp,
    const float* __restrict__ w_out, const float* __restrict__ b_out,
    float* __restrict__ out, int n0){
  __shared__ float sacc[128];
  int i2 = blockIdx.x; int nl = blockIdx.y;
  int n = n0 + nl;
  int tid = threadIdx.x;
  int f = *flagp;
  if (tid < 128){
    float a = 0.f;
    for (int k = 0; k < 8; k++){
      int e = n*8 + k;
      if (!mask_at(maskp, f, e)) a += R[(size_t)(nl*8+k)*1152 + i2*128 + tid];
    }
    sacc[tid] = a;
  }
  __syncthreads();
  int o = tid;
  int deg = d_DEG[i2];
  const float* wp = w_out + (size_t)deg*32768 + o;
  float s = (i2==0) ? b_out[o] : 0.f;
  #pragma unroll 4
  for (int c = 0; c < 128; c += 4){
    float4 a = *(const float4*)&sacc[c];
    s += a.x*wp[(size_t)c*256] + a.y*wp[(size_t)(c+1)*256]
       + a.z*wp[(size_t)(c+2)*256] + a.w*wp[(size_t)(c+3)*256];
  }
  out[((size_t)n*9 + i2)*256 + o] = s;
}

// ================= fallback mega kernel (round-5, pass-verified) =================
__device__ __forceinline__ float dotW(const float* __restrict__ A, const float* __restrict__ Wm, int K){
  float s = 0.f;
  #pragma unroll 4
  for (int i=0;i<K;i+=4){
    float4 a = *(const float4*)&A[i];
    s += a.x*Wm[(size_t)i*128] + a.y*Wm[(size_t)(i+1)*128]
       + a.z*Wm[(size_t)(i+2)*128] + a.w*Wm[(size_t)(i+3)*128];
  }
  return s;
}
__device__ __forceinline__ float dot2W(const float* __restrict__ P0, const float* __restrict__ P1,
    const float* __restrict__ W0, const float* __restrict__ W1, int ldw){
  float s = 0.f;
  #pragma unroll 4
  for (int k=0;k<128;k+=4){
    float4 a = *(const float4*)&P0[k];
    float4 b = *(const float4*)&P1[k];
    s += a.x*W0[(size_t)k*ldw] + a.y*W0[(size_t)(k+1)*ldw] + a.z*W0[(size_t)(k+2)*ldw] + a.w*W0[(size_t)(k+3)*ldw];
    s += b.x*W1[(size_t)k*ldw] + b.y*W1[(size_t)(k+1)*ldw] + b.z*W1[(size_t)(k+2)*ldw] + b.w*W1[(size_t)(k+3)*ldw];
  }
  return s;
}

__global__ __launch_bounds__(256) void k_mega(
    const float* __restrict__ x,      const float* __restrict__ w_in,  const float* __restrict__ b_in,
    const float* __restrict__ attn,
    const float* __restrict__ fdw,    const float* __restrict__ fdb,
    const float* __restrict__ few,    const float* __restrict__ feb,
    const float* __restrict__ es,     const float* __restrict__ et,
    const int*   __restrict__ an,     const int*   __restrict__ esrc,
    const float* __restrict__ d0w,    const float* __restrict__ d0b,
    const float* __restrict__ m1dw,   const float* __restrict__ m1db,
    const float* __restrict__ m2dw,   const float* __restrict__ m2db,
    const float* __restrict__ m0w1,   const float* __restrict__ m0w2,
    const float* __restrict__ m1w1r,  const float* __restrict__ m1w2r,
    const float* __restrict__ m1w1i,  const float* __restrict__ m1w2i,
    const float* __restrict__ m2w1r,  const float* __restrict__ m2w2r,
    const float* __restrict__ m2w1i,  const float* __restrict__ m2w2i,
    const float* __restrict__ wig,    const float* __restrict__ tg,   const float* __restrict__ fg,
    const float* __restrict__ w_out,  const float* __restrict__ b_out,
    const void*  __restrict__ maskp,  const int* __restrict__ flagp,
    float* __restrict__ out)
{
  __shared__ float S[7168];
  float* acc  = S;
  float* xs   = S + 1152;
  float* xtl  = S + 2304;
  float* Zb   = S + 1152;
  float* gg   = S + 3456;
  float* Yb   = S + 3456;
  float* P    = S + 4736;
  float* wl   = S + 7040;
  float* xe16 = S + 7124;
  float* xv   = S + 7140;

  const int n   = blockIdx.x;
  const int tid = threadIdx.x;
  const int f   = *flagp;

  for (int i = tid; i < 1152; i += 256) acc[i] = 0.f;

  for (int k = 0; k < 8; k++){
    int e = n*8 + k;
    if (mask_at(maskp, f, e)) continue;
    int src = esrc[e];
    __syncthreads();
    for (int i = tid; i < 81; i += 256) wl[i] = wig[(size_t)e*81 + i];
    if (tid < 16){
      int j = tid;
      float s = fdb[j] + es[(size_t)an[src]*16 + j] + et[(size_t)an[n]*16 + j];
      for (int kk = 0; kk < 32; kk++) s += attn[(size_t)e*32 + kk] * fdw[kk*16 + j];
      xv[j] = silu_f(s);
    }
    for (int idx = tid; idx < 2304; idx += 256){
      int which = idx >= 1152;
      int lidx = idx - which*1152;
      int j = lidx >> 7, c = lidx & 127;
      int deg = d_DEG[j];
      const float* wp = w_in + (size_t)deg*32768 + c;
      const float* xp = x + ((size_t)(which ? n : src)*9 + j)*256;
      float s = (j==0) ? b_in[c] : 0.f;
      for (int cc = 0; cc < 256; cc++) s += xp[cc] * wp[cc*128];
      P[idx] = s;
    }
    __syncthreads();
    if (tid < 16){
      int j = tid;
      float s = feb[j];
      for (int kk = 0; kk < 16; kk++) s += xv[kk] * few[kk*16 + j];
      xe16[j] = silu_f(s);
    }
    for (int idx = tid; idx < 1152; idx += 256){
      int p = idx >> 7, c = idx & 127;
      int ch = d_PERM[p];
      float s1 = 0.f, s2 = 0.f;
      #pragma unroll
      for (int j = 0; j < 9; j++){
        float wv = wl[ch*9 + j];
        s1 += wv * P[j*128 + c];
        s2 += wv * P[1152 + j*128 + c];
      }
      xs[idx]  = s1;
      xtl[idx] = s2;
    }
    __syncthreads();
    for (int col = tid; col < 1280; col += 256){
      int b = col / 640, r = col % 640;
      const float* w; float bias; int ldw, c2;
      if (r < 128){       w = d0w  + (size_t)b*2048; c2 = r;     ldw = 128; bias = d0b[b*128 + c2]; }
      else if (r < 384){  w = m1dw + (size_t)b*4096; c2 = r-128; ldw = 256; bias = m1db[b*256 + c2]; }
      else {              w = m2dw + (size_t)b*4096; c2 = r-384; ldw = 256; bias = m2db[b*256 + c2]; }
      float s = bias;
      #pragma unroll
      for (int kk = 0; kk < 16; kk++) s += xe16[kk] * w[kk*ldw + c2];
      gg[col] = silu_f(s);
    }
    __syncthreads();
    for (int o = tid; o < 2304; o += 256){
      float s;
      if (o < 256){
        int path = o >> 7, h = o & 127;
        s = dotW(path ? xtl : xs, m0w1 + (size_t)path*49152 + h, 384);
      } else if (o < 1280){
        int q = (o-256) >> 8; int rem = (o-256) & 255; int t = rem >> 7, h = rem & 127;
        const float* A  = ((q>=2) ? xtl : xs) + 384 + t*256;
        const float* Wm = ((q&1) ? m1w1i : m1w1r) + (size_t)((q>=2)?1:0)*32768 + h;
        s = dotW(A, Wm, 256);
      } else {
        int q = (o-1280) >> 8; int rem = (o-1280) & 255; int t = rem >> 7, h = rem & 127;
        const float* A  = ((q>=2) ? xtl : xs) + 896 + t*128;
        const float* Wm = ((q&1) ? m2w1i : m2w1r) + (size_t)((q>=2)?1:0)*16384 + h;
        s = dotW(A, Wm, 128);
      }
      P[o] = s;
    }
    __syncthreads();
    for (int o = tid; o < 2304; o += 256){
      int h = o & 127, goff;
      if (o < 256) goff = (o >> 7) ? 640 : 0;
      else if (o < 1280){ int q = (o-256) >> 8;  goff = 128 + (q&1)*128 + (q>>1)*640; }
      else              { int q = (o-1280) >> 8; goff = 384 + (q&1)*128 + (q>>1)*640; }
      P[o] *= gg[goff + h];
    }
    __syncthreads();
    for (int o = tid; o < 1152; o += 256){
      float s; int ch, c;
      if (o < 384){
        int g = o >> 7; c = o & 127;
        ch = (g==0) ? 0 : ((g==1) ? 2 : 6);
        const float* w0 = m0w2 + o;
        s = dot2W(P, P+128, w0, w0+49152, 384);
      } else if (o < 896){
        int om = o - 384; int tp = om >> 8; int col = om & 255;
        int g = col >> 7; c = col & 127;
        ch = tp ? (g ? 5 : 1) : (g ? 7 : 3);
        float sgn = tp ? 1.f : -1.f;
        const float* wr = m1w2r + col;
        const float* wi = m1w2i + col;
        s = dot2W(P+256+tp*128,     P+768+tp*128,     wr, wr+32768, 256)
          + sgn * dot2W(P+512+(1-tp)*128, P+1024+(1-tp)*128, wi, wi+32768, 256);
      } else {
        int om = o - 896; int tp = om >> 7; c = om & 127;
        ch = tp ? 4 : 8;
        float sgn = tp ? 1.f : -1.f;
        const float* wr = m2w2r + c;
        const float* wi = m2w2i + c;
        s = dot2W(P+1280+tp*128,     P+1792+tp*128,     wr, wr+16384, 128)
          + sgn * dot2W(P+1536+(1-tp)*128, P+2048+(1-tp)*128, wi, wi+16384, 128);
      }
      Yb[ch*128 + c] = s;
    }
    __syncthreads();
    {
      int half = tid >> 7, c = tid & 127;
      float z[9];
      #pragma unroll
      for (int i = 0; i < 9; i++) z[i] = 0.f;
      float y[9];
      #pragma unroll
      for (int i = 0; i < 9; i++) y[i] = Yb[i*128 + c];
      int p0 = half*162, p1 = p0 + 162;
      #pragma unroll 2
      for (int p = p0; p < p1; p++){
        float gp = 0.f;
        #pragma unroll
        for (int i = 0; i < 9; i++) gp += tg[p*9 + i] * y[i];
        float s = silu_f(gp);
        #pragma unroll
        for (int i = 0; i < 9; i++) z[i] += fg[p*9 + i] * s;
      }
      #pragma unroll
      for (int i = 0; i < 9; i++) Zb[half*1152 + i*128 + c] = z[i];
    }
    __syncthreads();
    for (int idx = tid; idx < 1152; idx += 256){
      int i2 = idx >> 7, c = idx & 127;
      float s = 0.f;
      #pragma unroll
      for (int j = 0; j < 9; j++)
        s += wl[j*9 + i2] * (Zb[j*128 + c] + Zb[1152 + j*128 + c]);
      acc[idx] += s;
    }
  }
  __syncthreads();
  {
    int o = tid;
    for (int i2 = 0; i2 < 9; i2++){
      int deg = d_DEG[i2];
      const float* wp = w_out + (size_t)deg*32768 + o;
      float s = (i2==0) ? b_out[o] : 0.f;
      #pragma unroll 4
      for (int c = 0; c < 128; c += 4){
        float4 a = *(const float4*)&acc[i2*128 + c];
        s += a.x*wp[(size_t)c*256] + a.y*wp[(size_t)(c+1)*256]
           + a.z*wp[(size_t)(c+2)*256] + a.w*wp[(size_t)(c+3)*256];
      }
      out[((size_t)n*9 + i2)*256 + o] = s;
    }
  }
}

// ---------------- host ----------------
extern "C" void kernel_launch(void* const* d_in, const int* in_sizes, int n_in,
                              void* d_out, int out_size, void* d_ws, size_t ws_size,
                              hipStream_t stream){
  const float* x     = (const float*)d_in[0];
  const float* attn  = (const float*)d_in[1];
  const float* wig   = (const float*)d_in[2];
  const float* tg    = (const float*)d_in[3];
  const float* fg    = (const float*)d_in[4];
  const float* w_in  = (const float*)d_in[5];
  const float* b_in  = (const float*)d_in[6];
  const float* w_out = (const float*)d_in[7];
  const float* b_out = (const float*)d_in[8];
  const float* es    = (const float*)d_in[9];
  const float* et    = (const float*)d_in[10];
  const float* fdw   = (const float*)d_in[11];
  const float* fdb   = (const float*)d_in[12];
  const float* few   = (const float*)d_in[13];
  const float* feb   = (const float*)d_in[14];
  const float* d0w   = (const float*)d_in[15];
  const float* d0b   = (const float*)d_in[16];
  const float* m0w1  = (const float*)d_in[17];
  const float* m0w2  = (const float*)d_in[18];
  const float* m1dw  = (const float*)d_in[19];
  const float* m1db  = (const float*)d_in[20];
  const float* m1w1r = (const float*)d_in[21];
  const float* m1w2r = (const float*)d_in[22];
  const float* m1w1i = (const float*)d_in[23];
  const float* m1w2i = (const float*)d_in[24];
  const float* m2dw  = (const float*)d_in[25];
  const float* m2db  = (const float*)d_in[26];
  const float* m2w1r = (const float*)d_in[27];
  const float* m2w2r = (const float*)d_in[28];
  const float* m2w1i = (const float*)d_in[29];
  const float* m2w2i = (const float*)d_in[30];
  const int*   an    = (const int*)d_in[31];
  const int*   esrc  = (const int*)d_in[32];
  const void*  maskp = d_in[33];

  float* W  = (float*)d_ws;
  int* FLAG = (int*)d_ws;
  float* Hg  = W + 16;         // 589824
  float* XEg = W + 589840;     // 65536
  float* XS  = W + 655376;     // 2359296 (2048*1152)
  float* XT  = W + 3014672;    // 2359296
  float* Gg  = W + 5373968;    // 2621440 (2048*1280)
  float* Pg  = W + 7995408;    // 4718592 (2048*2304)
  float* Yc  = XS;             // alias: XS dead after k_gs1
  float* Rc  = XT;             // alias: XT dead after k_gs1
  size_t need_new = (size_t)12714000 * 4;

  k_detect<<<1,256,0,stream>>>((const unsigned int*)maskp, FLAG);

  if (ws_size >= need_new){
    k_h<<<dim3(32,9),128,0,stream>>>(x, w_in, b_in, Hg);
    k_xe<<<16,256,0,stream>>>(attn, fdw, fdb, few, feb, es, et, an, esrc, XEg);
    for (int c2 = 0; c2 < 2; c2++){
      int e0 = c2*2048, n0 = c2*256;
      k_rotgate<<<2048,256,0,stream>>>(Hg, XEg, esrc, wig,
          d0w, d0b, m1dw, m1db, m2dw, m2db, XS, XT, Gg, e0);
      k_gs1<<<1152,256,0,stream>>>(XS, XT, Gg,
          m0w1, m1w1r, m1w1i, m2w1r, m2w1i, Pg);
      k_gs2<<<576,256,0,stream>>>(Pg, m0w2, m1w2r, m1w2i, m2w2r, m2w2i, Yc);
      k_grid2<<<2048,256,0,stream>>>(Yc, wig, tg, fg, maskp, FLAG, Rc, e0);
      k_redout<<<dim3(9,256),256,0,stream>>>(Rc, maskp, FLAG, w_out, b_out, (float*)d_out, n0);
    }
  } else {
    k_mega<<<512,256,0,stream>>>(
        x, w_in, b_in, attn, fdw, fdb, few, feb, es, et, an, esrc,
        d0w, d0b, m1dw, m1db, m2dw, m2db,
        m0w1, m0w2, m1w1r, m1w2r, m1w1i, m1w2i, m2w1r, m2w2r, m2w1i, m2w2i,
        wig, tg, fg, w_out, b_out, maskp, FLAG, (float*)d_out);
  }
}

// Round 10
// 437.002 us; speedup vs baseline: 1.3213x; 1.3213x over previous
//
#include <hip/hip_runtime.h>
#include <math.h>

__device__ const int d_PERM[9] = {0,2,6,3,7,1,5,8,4};
__device__ const int d_DEG[9]  = {0,1,1,1,2,2,2,2,2};

__device__ __forceinline__ float silu_f(float x){ return x / (1.0f + __expf(-x)); }
__device__ __forceinline__ float silu_fast(float x){ return x * __fdividef(1.0f, 1.0f + __expf(-x)); }

// flag: 0 = int32 words, 1 = u8 bytes, 2 = float32 words, 3 = int64 (low word)
__device__ __forceinline__ int mask_at(const void* mp, int flag, int e){
  if (flag==1) return ((const unsigned char*)mp)[e] != 0;
  if (flag==3) return ((const unsigned int*)mp)[2*e] != 0u;
  return ((const unsigned int*)mp)[e] != 0u;
}

__global__ void k_detect(const unsigned int* __restrict__ w, int* __restrict__ flag){
  __shared__ int notI, notF, anyOdd, anyEven;
  if (threadIdx.x==0){ notI=0; notF=0; anyOdd=0; anyEven=0; }
  __syncthreads();
  int li=0, lf=0, lo=0, le=0;
  for (int i = threadIdx.x; i < 1024; i += 256){
    unsigned int v = w[i];
    if (v != 0u && v != 1u) li = 1;
    if (v != 0u && v != 0x3F800000u) lf = 1;
    if (v != 0u){ if (i & 1) lo = 1; else le = 1; }
  }
  if (li) atomicOr(&notI,1);
  if (lf) atomicOr(&notF,1);
  if (lo) atomicOr(&anyOdd,1);
  if (le) atomicOr(&anyEven,1);
  __syncthreads();
  if (threadIdx.x==0){
    int f;
    if (!notI) f = (anyOdd || !anyEven) ? 0 : 3;
    else       f = (!notF) ? 2 : 1;
    *flag = f;
  }
}

// ---------------- H = x @ w_in[DEG] (+b_in at j==0), (N,9,128) ----------------
__global__ __launch_bounds__(128) void k_h(const float* __restrict__ x,
    const float* __restrict__ w_in, const float* __restrict__ b_in,
    float* __restrict__ H){
  __shared__ float xl[16][260];
  int i = blockIdx.y; int n0 = blockIdx.x*16;
  int deg = d_DEG[i];
  for (int idx = threadIdx.x; idx < 16*256; idx += 128){
    int r = idx >> 8, c = idx & 255;
    xl[r][c] = x[((size_t)(n0+r)*9 + i)*256 + c];
  }
  __syncthreads();
  int o = threadIdx.x;
  float acc[16];
  #pragma unroll
  for (int r=0;r<16;r++) acc[r]=0.f;
  const float* w = w_in + (size_t)deg*32768 + o;
  for (int c=0;c<256;c+=4){
    float w0=w[(size_t)c*128], w1=w[(size_t)(c+1)*128], w2=w[(size_t)(c+2)*128], w3=w[(size_t)(c+3)*128];
    #pragma unroll
    for (int r=0;r<16;r++){
      float4 xv4 = *(const float4*)&xl[r][c];
      acc[r] += xv4.x*w0 + xv4.y*w1 + xv4.z*w2 + xv4.w*w3;
    }
  }
  float bb = (i==0)? b_in[o] : 0.f;
  #pragma unroll
  for (int r=0;r<16;r++) H[((size_t)(n0+r)*9+i)*128+o] = acc[r]+bb;
}

// ---------------- XE (E,16) ----------------
__global__ __launch_bounds__(256) void k_xe(const float* __restrict__ attn,
    const float* __restrict__ fdw, const float* __restrict__ fdb,
    const float* __restrict__ few, const float* __restrict__ feb,
    const float* __restrict__ es, const float* __restrict__ et,
    const int* __restrict__ an, const int* __restrict__ esrc,
    float* __restrict__ XE){
  int e = blockIdx.x*256 + threadIdx.x;
  float aw[32];
  #pragma unroll
  for (int k=0;k<32;k+=4){
    float4 v = *(const float4*)&attn[(size_t)e*32+k];
    aw[k]=v.x; aw[k+1]=v.y; aw[k+2]=v.z; aw[k+3]=v.w;
  }
  int src = esrc[e]; int tgt = e>>3;
  int za = an[src], zb = an[tgt];
  float v0[16];
  #pragma unroll
  for (int j=0;j<16;j++){
    float s = fdb[j] + es[(size_t)za*16+j] + et[(size_t)zb*16+j];
    #pragma unroll
    for (int k=0;k<32;k++) s += aw[k]*fdw[k*16+j];
    v0[j] = silu_f(s);
  }
  #pragma unroll
  for (int j=0;j<16;j++){
    float s = feb[j];
    #pragma unroll
    for (int k=0;k<16;k++) s += v0[k]*few[k*16+j];
    XE[(size_t)e*16+j] = silu_f(s);
  }
}

// ================= rotate + gates (per edge, dense) =================
__global__ __launch_bounds__(256) void k_rotgate(
    const float* __restrict__ Hg, const float* __restrict__ XEg,
    const int* __restrict__ esrc, const float* __restrict__ wig,
    const float* __restrict__ d0w,  const float* __restrict__ d0b,
    const float* __restrict__ m1dw, const float* __restrict__ m1db,
    const float* __restrict__ m2dw, const float* __restrict__ m2db,
    float* __restrict__ XS, float* __restrict__ XT, float* __restrict__ G,
    int e0)
{
  __shared__ float xe16[16];
  int el = blockIdx.x;
  int e = e0 + el;
  int tid = threadIdx.x;
  int n = e >> 3, src = esrc[e];
  if (tid < 16) xe16[tid] = XEg[(size_t)e*16 + tid];
  for (int idx = tid; idx < 1152; idx += 256){
    int p = idx >> 7, c = idx & 127;
    int ch = d_PERM[p];
    const float* wr = wig + (size_t)e*81 + ch*9;
    const float* hs = Hg + (size_t)src*1152 + c;
    const float* ht = Hg + (size_t)n*1152 + c;
    float s1 = 0.f, s2 = 0.f;
    #pragma unroll
    for (int j = 0; j < 9; j++){
      float wv = wr[j];
      s1 += wv * hs[j*128];
      s2 += wv * ht[j*128];
    }
    XS[(size_t)el*1152 + idx] = s1;
    XT[(size_t)el*1152 + idx] = s2;
  }
  __syncthreads();
  for (int col = tid; col < 1280; col += 256){
    int b = col / 640, r = col % 640;
    const float* w; float bias; int ldw, c2;
    if (r < 128){       w = d0w  + (size_t)b*2048; c2 = r;     ldw = 128; bias = d0b[b*128 + c2]; }
    else if (r < 384){  w = m1dw + (size_t)b*4096; c2 = r-128; ldw = 256; bias = m1db[b*256 + c2]; }
    else {              w = m2dw + (size_t)b*4096; c2 = r-384; ldw = 256; bias = m2db[b*256 + c2]; }
    float s = bias;
    #pragma unroll
    for (int kk = 0; kk < 16; kk++) s += xe16[kk] * w[kk*ldw + c2];
    G[(size_t)el*1280 + col] = silu_f(s);
  }
}

// ================= stage-1 tiled GEMM (all regions in one launch) =================
__global__ __launch_bounds__(256) void k_gs1(
    const float* __restrict__ XS, const float* __restrict__ XT,
    const float* __restrict__ G,
    const float* __restrict__ m0w1,
    const float* __restrict__ m1w1r, const float* __restrict__ m1w1i,
    const float* __restrict__ m2w1r, const float* __restrict__ m2w1i,
    float* __restrict__ Pg)
{
  __shared__ float As[16][68];
  __shared__ float Bs[16][68];
  int b = blockIdx.x;
  int t = threadIdx.x;
  const float* Ax; const float* Bw;
  int K, bm, hbase, obase, goff, rsh, aoff, tstride;
  if (b < 128){
    int mt = b>>2, nt = b&3;
    int path = nt>>1;
    Ax = path ? XT : XS;
    Bw = m0w1 + (size_t)path*49152 + (nt&1)*64;
    K = 384; bm = mt*64; hbase = (nt&1)*64;
    obase = path*128; goff = path ? 640 : 0;
    rsh = 0; aoff = 0; tstride = 0;
  } else if (b < 640){
    int i = b-128; int q = i>>7; int rr = i&127; int mt = rr>>1, nt = rr&1;
    Ax = (q>=2) ? XT : XS;
    Bw = ((q&1) ? m1w1i : m1w1r) + (size_t)((q>=2)?1:0)*32768 + nt*64;
    K = 256; bm = mt*64; hbase = nt*64;
    obase = 256 + q*256; goff = 128 + (q&1)*128 + (q>>1)*640;
    rsh = 1; aoff = 384; tstride = 256;
  } else {
    int i = b-640; int q = i>>7; int rr = i&127; int mt = rr>>1, nt = rr&1;
    Ax = (q>=2) ? XT : XS;
    Bw = ((q&1) ? m2w1i : m2w1r) + (size_t)((q>=2)?1:0)*16384 + nt*64;
    K = 128; bm = mt*64; hbase = nt*64;
    obase = 1280 + q*256; goff = 384 + (q&1)*128 + (q>>1)*640;
    rsh = 1; aoff = 896; tstride = 128;
  }
  int ar = t>>2, ak = (t&3)*4;
  int am = bm + ar;
  int ael = am >> rsh, atp = am & rsh;
  const float* aptr = Ax + (size_t)ael*1152 + aoff + atp*tstride + ak;
  int kb = t>>4, nbb = (t&15)*4;
  const float* bptr = Bw + (size_t)kb*128 + nbb;
  int tx = t&15, ty = t>>4;
  float acc[4][4];
  #pragma unroll
  for (int i2=0;i2<4;i2++){ acc[i2][0]=0.f; acc[i2][1]=0.f; acc[i2][2]=0.f; acc[i2][3]=0.f; }
  for (int k0=0;k0<K;k0+=16){
    float4 av = *(const float4*)(aptr + k0);
    float4 bv = *(const float4*)(bptr + (size_t)k0*128);
    As[ak+0][ar]=av.x; As[ak+1][ar]=av.y; As[ak+2][ar]=av.z; As[ak+3][ar]=av.w;
    *(float4*)&Bs[kb][nbb] = bv;
    __syncthreads();
    #pragma unroll
    for (int k=0;k<16;k++){
      float4 a4 = *(const float4*)&As[k][ty*4];
      float4 b4 = *(const float4*)&Bs[k][tx*4];
      acc[0][0]+=a4.x*b4.x; acc[0][1]+=a4.x*b4.y; acc[0][2]+=a4.x*b4.z; acc[0][3]+=a4.x*b4.w;
      acc[1][0]+=a4.y*b4.x; acc[1][1]+=a4.y*b4.y; acc[1][2]+=a4.y*b4.z; acc[1][3]+=a4.y*b4.w;
      acc[2][0]+=a4.z*b4.x; acc[2][1]+=a4.z*b4.y; acc[2][2]+=a4.z*b4.z; acc[2][3]+=a4.z*b4.w;
      acc[3][0]+=a4.w*b4.x; acc[3][1]+=a4.w*b4.y; acc[3][2]+=a4.w*b4.z; acc[3][3]+=a4.w*b4.w;
    }
    __syncthreads();
  }
  #pragma unroll
  for (int i2=0;i2<4;i2++){
    int m = bm + ty*4 + i2;
    int el = m >> rsh, tp = m & rsh;
    int h = hbase + tx*4;
    float4 gv = *(const float4*)&G[(size_t)el*1280 + goff + h];
    float4 v = make_float4(acc[i2][0]*gv.x, acc[i2][1]*gv.y, acc[i2][2]*gv.z, acc[i2][3]*gv.w);
    *(float4*)&Pg[(size_t)el*2304 + obase + tp*128 + h] = v;
  }
}

// ================= stage-2 tiled GEMM -> Y (orig channel order) =================
__global__ __launch_bounds__(256) void k_gs2(
    const float* __restrict__ Pg,
    const float* __restrict__ m0w2,
    const float* __restrict__ m1w2r, const float* __restrict__ m1w2i,
    const float* __restrict__ m2w2r, const float* __restrict__ m2w2i,
    float* __restrict__ Y)
{
  __shared__ float As[16][68];
  __shared__ float Bs[16][68];
  int b = blockIdx.x;
  int t = threadIdx.x;
  int region, bm, ncolbase, K;
  if (b < 192){ region=0; int mt=b/6, nt=b-mt*6; bm=mt*64; ncolbase=nt*64; K=256; }
  else if (b < 448){ region=1; int i=b-192; int mt=i>>2, nt=i&3; bm=mt*64; ncolbase=nt*64; K=512; }
  else { region=2; int i=b-448; int mt=i>>1, nt=i&1; bm=mt*64; ncolbase=nt*64; K=512; }

  int ar = t>>2, ak = (t&3)*4;
  int am = bm + ar;
  int kb = t>>4, nbb = (t&15)*4;
  int tx = t&15, ty = t>>4;
  float acc[4][4];
  #pragma unroll
  for (int i2=0;i2<4;i2++){ acc[i2][0]=0.f; acc[i2][1]=0.f; acc[i2][2]=0.f; acc[i2][3]=0.f; }

  int ael, atp; float asgn_base;
  if (region==0){ ael = am; atp = 0; asgn_base = 1.f; }
  else { ael = am>>1; atp = am&1; asgn_base = atp ? 1.f : -1.f; }
  int segbase0 = (region==2) ? 1280 : 256;

  for (int k0=0;k0<K;k0+=16){
    float4 av;
    if (region==0){
      av = *(const float4*)(Pg + (size_t)ael*2304 + k0 + ak);
    } else {
      int ks = k0 + ak;
      int seg = ks>>7, kk = ks&127;
      int tsel = (seg&1) ? (1-atp) : atp;
      float sg = (seg&1) ? asgn_base : 1.f;
      av = *(const float4*)(Pg + (size_t)ael*2304 + segbase0 + seg*256 + tsel*128 + kk);
      av.x *= sg; av.y *= sg; av.z *= sg; av.w *= sg;
    }
    float4 bv;
    int ks2 = k0 + kb;
    if (region==0){
      bv = *(const float4*)(m0w2 + (size_t)(ks2>>7)*49152 + (size_t)(ks2&127)*384 + ncolbase + nbb);
    } else if (region==1){
      const float* base = ((ks2>>7)&1) ? m1w2i : m1w2r;
      bv = *(const float4*)(base + (size_t)(ks2>>8)*32768 + (size_t)(ks2&127)*256 + ncolbase + nbb);
    } else {
      const float* base = ((ks2>>7)&1) ? m2w2i : m2w2r;
      bv = *(const float4*)(base + (size_t)(ks2>>8)*16384 + (size_t)(ks2&127)*128 + ncolbase + nbb);
    }
    As[ak+0][ar]=av.x; As[ak+1][ar]=av.y; As[ak+2][ar]=av.z; As[ak+3][ar]=av.w;
    *(float4*)&Bs[kb][nbb] = bv;
    __syncthreads();
    #pragma unroll
    for (int k=0;k<16;k++){
      float4 a4 = *(const float4*)&As[k][ty*4];
      float4 b4 = *(const float4*)&Bs[k][tx*4];
      acc[0][0]+=a4.x*b4.x; acc[0][1]+=a4.x*b4.y; acc[0][2]+=a4.x*b4.z; acc[0][3]+=a4.x*b4.w;
      acc[1][0]+=a4.y*b4.x; acc[1][1]+=a4.y*b4.y; acc[1][2]+=a4.y*b4.z; acc[1][3]+=a4.y*b4.w;
      acc[2][0]+=a4.z*b4.x; acc[2][1]+=a4.z*b4.y; acc[2][2]+=a4.z*b4.z; acc[2][3]+=a4.z*b4.w;
      acc[3][0]+=a4.w*b4.x; acc[3][1]+=a4.w*b4.y; acc[3][2]+=a4.w*b4.z; acc[3][3]+=a4.w*b4.w;
    }
    __syncthreads();
  }
  #pragma unroll
  for (int i2=0;i2<4;i2++){
    int m = bm + ty*4 + i2;
    int el, tp;
    if (region==0){ el = m; tp = 0; } else { el = m>>1; tp = m&1; }
    int col = ncolbase + tx*4;
    int g = col >> 7, c = col & 127;
    int ch;
    if (region==0)      ch = (g==0) ? 0 : ((g==1) ? 2 : 6);
    else if (region==1) ch = tp ? (g ? 5 : 1) : (g ? 7 : 3);
    else                ch = tp ? 4 : 8;
    float4 v = make_float4(acc[i2][0],acc[i2][1],acc[i2][2],acc[i2][3]);
    *(float4*)&Y[(size_t)el*1152 + ch*128 + c] = v;
  }
}

// ================= grid transform: 2 edges/block, LDS coeffs, fused A8 =================
// LDS: cf[324*24] (tg @ +0..8, fg @ +12..20, 16B-aligned) | wl[2*81]
__global__ __launch_bounds__(256, 4) void k_grid3(const float* __restrict__ Y,
    const float* __restrict__ wig, const float* __restrict__ tg, const float* __restrict__ fg,
    const void* __restrict__ maskp, const int* __restrict__ flagp,
    float* __restrict__ R, int e0)
{
  __shared__ float cf[324*24];
  __shared__ float wl[2*81];
  int tid = threadIdx.x;
  int el0 = blockIdx.x*2;

  // stage coefficients (coalesced global reads, strided LDS writes)
  for (int idx = tid; idx < 2916; idx += 256){
    int p = idx / 9, i = idx - p*9;
    cf[p*24 + i]      = tg[idx];
    cf[p*24 + 12 + i] = fg[idx];
  }
  // stage wigner for both edges
  for (int i = tid; i < 162; i += 256){
    int eL2 = i / 81, ii = i - eL2*81;
    wl[i] = wig[(size_t)(e0 + el0 + eL2)*81 + ii];
  }
  __syncthreads();

  int eL = tid >> 7, c = tid & 127;
  int el = el0 + eL;
  int e = e0 + el;
  if (mask_at(maskp, *flagp, e)) return;   // no barriers after this point

  float y[9], z[9];
  #pragma unroll
  for (int i = 0; i < 9; i++){
    y[i] = Y[(size_t)el*1152 + i*128 + c];
    z[i] = 0.f;
  }

  #pragma unroll 2
  for (int p = 0; p < 324; p++){
    const float* cp = &cf[p*24];
    float4 t0 = *(const float4*)cp;
    float4 t1 = *(const float4*)(cp+4);
    float  t8 = cp[8];
    float gp = t0.x*y[0] + t0.y*y[1] + t0.z*y[2] + t0.w*y[3]
             + t1.x*y[4] + t1.y*y[5] + t1.z*y[6] + t1.w*y[7] + t8*y[8];
    float s = gp * __fdividef(1.0f, 1.0f + __expf(-gp));
    float4 f0 = *(const float4*)(cp+12);
    float4 f1 = *(const float4*)(cp+16);
    float  f8 = cp[20];
    z[0] += f0.x*s; z[1] += f0.y*s; z[2] += f0.z*s; z[3] += f0.w*s;
    z[4] += f1.x*s; z[5] += f1.y*s; z[6] += f1.z*s; z[7] += f1.w*s; z[8] += f8*s;
  }

  // A8: wigner-transpose in registers
  const float* wle = &wl[eL*81];
  #pragma unroll
  for (int i2 = 0; i2 < 9; i2++){
    float s = 0.f;
    #pragma unroll
    for (int j = 0; j < 9; j++) s += wle[j*9 + i2] * z[j];
    R[(size_t)el*1152 + i2*128 + c] = s;
  }
}

// ================= masked reduce + w_out projection (R chunk-local from atom n0) =========
__global__ __launch_bounds__(256) void k_redout(const float* __restrict__ R,
    const void* __restrict__ maskp, const int* __restrict__ flagp,
    const float* __restrict__ w_out, const float* __restrict__ b_out,
    float* __restrict__ out, int n0){
  __shared__ float sacc[128];
  int i2 = blockIdx.x; int nl = blockIdx.y;
  int n = n0 + nl;
  int tid = threadIdx.x;
  int f = *flagp;
  if (tid < 128){
    float a = 0.f;
    for (int k = 0; k < 8; k++){
      int e = n*8 + k;
      if (!mask_at(maskp, f, e)) a += R[(size_t)(nl*8+k)*1152 + i2*128 + tid];
    }
    sacc[tid] = a;
  }
  __syncthreads();
  int o = tid;
  int deg = d_DEG[i2];
  const float* wp = w_out + (size_t)deg*32768 + o;
  float s = (i2==0) ? b_out[o] : 0.f;
  #pragma unroll 4
  for (int c = 0; c < 128; c += 4){
    float4 a = *(const float4*)&sacc[c];
    s += a.x*wp[(size_t)c*256] + a.y*wp[(size_t)(c+1)*256]
       + a.z*wp[(size_t)(c+2)*256] + a.w*wp[(size_t)(c+3)*256];
  }
  out[((size_t)n*9 + i2)*256 + o] = s;
}

// ================= fallback mega kernel (round-5, pass-verified) =================
__device__ __forceinline__ float dotW(const float* __restrict__ A, const float* __restrict__ Wm, int K){
  float s = 0.f;
  #pragma unroll 4
  for (int i=0;i<K;i+=4){
    float4 a = *(const float4*)&A[i];
    s += a.x*Wm[(size_t)i*128] + a.y*Wm[(size_t)(i+1)*128]
       + a.z*Wm[(size_t)(i+2)*128] + a.w*Wm[(size_t)(i+3)*128];
  }
  return s;
}
__device__ __forceinline__ float dot2W(const float* __restrict__ P0, const float* __restrict__ P1,
    const float* __restrict__ W0, const float* __restrict__ W1, int ldw){
  float s = 0.f;
  #pragma unroll 4
  for (int k=0;k<128;k+=4){
    float4 a = *(const float4*)&P0[k];
    float4 b = *(const float4*)&P1[k];
    s += a.x*W0[(size_t)k*ldw] + a.y*W0[(size_t)(k+1)*ldw] + a.z*W0[(size_t)(k+2)*ldw] + a.w*W0[(size_t)(k+3)*ldw];
    s += b.x*W1[(size_t)k*ldw] + b.y*W1[(size_t)(k+1)*ldw] + b.z*W1[(size_t)(k+2)*ldw] + b.w*W1[(size_t)(k+3)*ldw];
  }
  return s;
}

__global__ __launch_bounds__(256) void k_mega(
    const float* __restrict__ x,      const float* __restrict__ w_in,  const float* __restrict__ b_in,
    const float* __restrict__ attn,
    const float* __restrict__ fdw,    const float* __restrict__ fdb,
    const float* __restrict__ few,    const float* __restrict__ feb,
    const float* __restrict__ es,     const float* __restrict__ et,
    const int*   __restrict__ an,     const int*   __restrict__ esrc,
    const float* __restrict__ d0w,    const float* __restrict__ d0b,
    const float* __restrict__ m1dw,   const float* __restrict__ m1db,
    const float* __restrict__ m2dw,   const float* __restrict__ m2db,
    const float* __restrict__ m0w1,   const float* __restrict__ m0w2,
    const float* __restrict__ m1w1r,  const float* __restrict__ m1w2r,
    const float* __restrict__ m1w1i,  const float* __restrict__ m1w2i,
    const float* __restrict__ m2w1r,  const float* __restrict__ m2w2r,
    const float* __restrict__ m2w1i,  const float* __restrict__ m2w2i,
    const float* __restrict__ wig,    const float* __restrict__ tg,   const float* __restrict__ fg,
    const float* __restrict__ w_out,  const float* __restrict__ b_out,
    const void*  __restrict__ maskp,  const int* __restrict__ flagp,
    float* __restrict__ out)
{
  __shared__ float S[7168];
  float* acc  = S;
  float* xs   = S + 1152;
  float* xtl  = S + 2304;
  float* Zb   = S + 1152;
  float* gg   = S + 3456;
  float* Yb   = S + 3456;
  float* P    = S + 4736;
  float* wl   = S + 7040;
  float* xe16 = S + 7124;
  float* xv   = S + 7140;

  const int n   = blockIdx.x;
  const int tid = threadIdx.x;
  const int f   = *flagp;

  for (int i = tid; i < 1152; i += 256) acc[i] = 0.f;

  for (int k = 0; k < 8; k++){
    int e = n*8 + k;
    if (mask_at(maskp, f, e)) continue;
    int src = esrc[e];
    __syncthreads();
    for (int i = tid; i < 81; i += 256) wl[i] = wig[(size_t)e*81 + i];
    if (tid < 16){
      int j = tid;
      float s = fdb[j] + es[(size_t)an[src]*16 + j] + et[(size_t)an[n]*16 + j];
      for (int kk = 0; kk < 32; kk++) s += attn[(size_t)e*32 + kk] * fdw[kk*16 + j];
      xv[j] = silu_f(s);
    }
    for (int idx = tid; idx < 2304; idx += 256){
      int which = idx >= 1152;
      int lidx = idx - which*1152;
      int j = lidx >> 7, c = lidx & 127;
      int deg = d_DEG[j];
      const float* wp = w_in + (size_t)deg*32768 + c;
      const float* xp = x + ((size_t)(which ? n : src)*9 + j)*256;
      float s = (j==0) ? b_in[c] : 0.f;
      for (int cc = 0; cc < 256; cc++) s += xp[cc] * wp[cc*128];
      P[idx] = s;
    }
    __syncthreads();
    if (tid < 16){
      int j = tid;
      float s = feb[j];
      for (int kk = 0; kk < 16; kk++) s += xv[kk] * few[kk*16 + j];
      xe16[j] = silu_f(s);
    }
    for (int idx = tid; idx < 1152; idx += 256){
      int p = idx >> 7, c = idx & 127;
      int ch = d_PERM[p];
      float s1 = 0.f, s2 = 0.f;
      #pragma unroll
      for (int j = 0; j < 9; j++){
        float wv = wl[ch*9 + j];
        s1 += wv * P[j*128 + c];
        s2 += wv * P[1152 + j*128 + c];
      }
      xs[idx]  = s1;
      xtl[idx] = s2;
    }
    __syncthreads();
    for (int col = tid; col < 1280; col += 256){
      int b = col / 640, r = col % 640;
      const float* w; float bias; int ldw, c2;
      if (r < 128){       w = d0w  + (size_t)b*2048; c2 = r;     ldw = 128; bias = d0b[b*128 + c2]; }
      else if (r < 384){  w = m1dw + (size_t)b*4096; c2 = r-128; ldw = 256; bias = m1db[b*256 + c2]; }
      else {              w = m2dw + (size_t)b*4096; c2 = r-384; ldw = 256; bias = m2db[b*256 + c2]; }
      float s = bias;
      #pragma unroll
      for (int kk = 0; kk < 16; kk++) s += xe16[kk] * w[kk*ldw + c2];
      gg[col] = silu_f(s);
    }
    __syncthreads();
    for (int o = tid; o < 2304; o += 256){
      float s;
      if (o < 256){
        int path = o >> 7, h = o & 127;
        s = dotW(path ? xtl : xs, m0w1 + (size_t)path*49152 + h, 384);
      } else if (o < 1280){
        int q = (o-256) >> 8; int rem = (o-256) & 255; int t = rem >> 7, h = rem & 127;
        const float* A  = ((q>=2) ? xtl : xs) + 384 + t*256;
        const float* Wm = ((q&1) ? m1w1i : m1w1r) + (size_t)((q>=2)?1:0)*32768 + h;
        s = dotW(A, Wm, 256);
      } else {
        int q = (o-1280) >> 8; int rem = (o-1280) & 255; int t = rem >> 7, h = rem & 127;
        const float* A  = ((q>=2) ? xtl : xs) + 896 + t*128;
        const float* Wm = ((q&1) ? m2w1i : m2w1r) + (size_t)((q>=2)?1:0)*16384 + h;
        s = dotW(A, Wm, 128);
      }
      P[o] = s;
    }
    __syncthreads();
    for (int o = tid; o < 2304; o += 256){
      int h = o & 127, goff;
      if (o < 256) goff = (o >> 7) ? 640 : 0;
      else if (o < 1280){ int q = (o-256) >> 8;  goff = 128 + (q&1)*128 + (q>>1)*640; }
      else              { int q = (o-1280) >> 8; goff = 384 + (q&1)*128 + (q>>1)*640; }
      P[o] *= gg[goff + h];
    }
    __syncthreads();
    for (int o = tid; o < 1152; o += 256){
      float s; int ch, c;
      if (o < 384){
        int g = o >> 7; c = o & 127;
        ch = (g==0) ? 0 : ((g==1) ? 2 : 6);
        const float* w0 = m0w2 + o;
        s = dot2W(P, P+128, w0, w0+49152, 384);
      } else if (o < 896){
        int om = o - 384; int tp = om >> 8; int col = om & 255;
        int g = col >> 7; c = col & 127;
        ch = tp ? (g ? 5 : 1) : (g ? 7 : 3);
        float sgn = tp ? 1.f : -1.f;
        const float* wr = m1w2r + col;
        const float* wi = m1w2i + col;
        s = dot2W(P+256+tp*128,     P+768+tp*128,     wr, wr+32768, 256)
          + sgn * dot2W(P+512+(1-tp)*128, P+1024+(1-tp)*128, wi, wi+32768, 256);
      } else {
        int om = o - 896; int tp = om >> 7; c = om & 127;
        ch = tp ? 4 : 8;
        float sgn = tp ? 1.f : -1.f;
        const float* wr = m2w2r + c;
        const float* wi = m2w2i + c;
        s = dot2W(P+1280+tp*128,     P+1792+tp*128,     wr, wr+16384, 128)
          + sgn * dot2W(P+1536+(1-tp)*128, P+2048+(1-tp)*128, wi, wi+16384, 128);
      }
      Yb[ch*128 + c] = s;
    }
    __syncthreads();
    {
      int half = tid >> 7, c = tid & 127;
      float z[9];
      #pragma unroll
      for (int i = 0; i < 9; i++) z[i] = 0.f;
      float y[9];
      #pragma unroll
      for (int i = 0; i < 9; i++) y[i] = Yb[i*128 + c];
      int p0 = half*162, p1 = p0 + 162;
      #pragma unroll 2
      for (int p = p0; p < p1; p++){
        float gp = 0.f;
        #pragma unroll
        for (int i = 0; i < 9; i++) gp += tg[p*9 + i] * y[i];
        float s = silu_f(gp);
        #pragma unroll
        for (int i = 0; i < 9; i++) z[i] += fg[p*9 + i] * s;
      }
      #pragma unroll
      for (int i = 0; i < 9; i++) Zb[half*1152 + i*128 + c] = z[i];
    }
    __syncthreads();
    for (int idx = tid; idx < 1152; idx += 256){
      int i2 = idx >> 7, c = idx & 127;
      float s = 0.f;
      #pragma unroll
      for (int j = 0; j < 9; j++)
        s += wl[j*9 + i2] * (Zb[j*128 + c] + Zb[1152 + j*128 + c]);
      acc[idx] += s;
    }
  }
  __syncthreads();
  {
    int o = tid;
    for (int i2 = 0; i2 < 9; i2++){
      int deg = d_DEG[i2];
      const float* wp = w_out + (size_t)deg*32768 + o;
      float s = (i2==0) ? b_out[o] : 0.f;
      #pragma unroll 4
      for (int c = 0; c < 128; c += 4){
        float4 a = *(const float4*)&acc[i2*128 + c];
        s += a.x*wp[(size_t)c*256] + a.y*wp[(size_t)(c+1)*256]
           + a.z*wp[(size_t)(c+2)*256] + a.w*wp[(size_t)(c+3)*256];
      }
      out[((size_t)n*9 + i2)*256 + o] = s;
    }
  }
}

// ---------------- host ----------------
extern "C" void kernel_launch(void* const* d_in, const int* in_sizes, int n_in,
                              void* d_out, int out_size, void* d_ws, size_t ws_size,
                              hipStream_t stream){
  const float* x     = (const float*)d_in[0];
  const float* attn  = (const float*)d_in[1];
  const float* wig   = (const float*)d_in[2];
  const float* tg    = (const float*)d_in[3];
  const float* fg    = (const float*)d_in[4];
  const float* w_in  = (const float*)d_in[5];
  const float* b_in  = (const float*)d_in[6];
  const float* w_out = (const float*)d_in[7];
  const float* b_out = (const float*)d_in[8];
  const float* es    = (const float*)d_in[9];
  const float* et    = (const float*)d_in[10];
  const float* fdw   = (const float*)d_in[11];
  const float* fdb   = (const float*)d_in[12];
  const float* few   = (const float*)d_in[13];
  const float* feb   = (const float*)d_in[14];
  const float* d0w   = (const float*)d_in[15];
  const float* d0b   = (const float*)d_in[16];
  const float* m0w1  = (const float*)d_in[17];
  const float* m0w2  = (const float*)d_in[18];
  const float* m1dw  = (const float*)d_in[19];
  const float* m1db  = (const float*)d_in[20];
  const float* m1w1r = (const float*)d_in[21];
  const float* m1w2r = (const float*)d_in[22];
  const float* m1w1i = (const float*)d_in[23];
  const float* m1w2i = (const float*)d_in[24];
  const float* m2dw  = (const float*)d_in[25];
  const float* m2db  = (const float*)d_in[26];
  const float* m2w1r = (const float*)d_in[27];
  const float* m2w2r = (const float*)d_in[28];
  const float* m2w1i = (const float*)d_in[29];
  const float* m2w2i = (const float*)d_in[30];
  const int*   an    = (const int*)d_in[31];
  const int*   esrc  = (const int*)d_in[32];
  const void*  maskp = d_in[33];

  float* W  = (float*)d_ws;
  int* FLAG = (int*)d_ws;
  float* Hg  = W + 16;         // 589824
  float* XEg = W + 589840;     // 65536
  float* XS  = W + 655376;     // 2359296 (2048*1152)
  float* XT  = W + 3014672;    // 2359296
  float* Gg  = W + 5373968;    // 2621440 (2048*1280)
  float* Pg  = W + 7995408;    // 4718592 (2048*2304)
  float* Yc  = XS;             // alias: XS dead after k_gs1
  float* Rc  = XT;             // alias: XT dead after k_gs1
  size_t need_new = (size_t)12714000 * 4;

  k_detect<<<1,256,0,stream>>>((const unsigned int*)maskp, FLAG);

  if (ws_size >= need_new){
    k_h<<<dim3(32,9),128,0,stream>>>(x, w_in, b_in, Hg);
    k_xe<<<16,256,0,stream>>>(attn, fdw, fdb, few, feb, es, et, an, esrc, XEg);
    for (int c2 = 0; c2 < 2; c2++){
      int e0 = c2*2048, n0 = c2*256;
      k_rotgate<<<2048,256,0,stream>>>(Hg, XEg, esrc, wig,
          d0w, d0b, m1dw, m1db, m2dw, m2db, XS, XT, Gg, e0);
      k_gs1<<<1152,256,0,stream>>>(XS, XT, Gg,
          m0w1, m1w1r, m1w1i, m2w1r, m2w1i, Pg);
      k_gs2<<<576,256,0,stream>>>(Pg, m0w2, m1w2r, m1w2i, m2w2r, m2w2i, Yc);
      k_grid3<<<1024,256,0,stream>>>(Yc, wig, tg, fg, maskp, FLAG, Rc, e0);
      k_redout<<<dim3(9,256),256,0,stream>>>(Rc, maskp, FLAG, w_out, b_out, (float*)d_out, n0);
    }
  } else {
    k_mega<<<512,256,0,stream>>>(
        x, w_in, b_in, attn, fdw, fdb, few, feb, es, et, an, esrc,
        d0w, d0b, m1dw, m1db, m2dw, m2db,
        m0w1, m0w2, m1w1r, m1w2r, m1w1i, m1w2i, m2w1r, m2w2r, m2w1i, m2w2i,
        wig, tg, fg, w_out, b_out, maskp, FLAG, (float*)d_out);
  }
}

// Round 11
// 370.693 us; speedup vs baseline: 1.5576x; 1.1789x over previous
//
#include <hip/hip_runtime.h>
#include <math.h>

__device__ const int d_PERM[9] = {0,2,6,3,7,1,5,8,4};
__device__ const int d_DEG[9]  = {0,1,1,1,2,2,2,2,2};

__device__ __forceinline__ float silu_f(float x){ return x / (1.0f + __expf(-x)); }

// flag: 0 = int32 words, 1 = u8 bytes, 2 = float32 words, 3 = int64 (low word)
__device__ __forceinline__ int mask_at(const void* mp, int flag, int e){
  if (flag==1) return ((const unsigned char*)mp)[e] != 0;
  if (flag==3) return ((const unsigned int*)mp)[2*e] != 0u;
  return ((const unsigned int*)mp)[e] != 0u;
}

__global__ void k_detect(const unsigned int* __restrict__ w, int* __restrict__ flag){
  __shared__ int notI, notF, anyOdd, anyEven;
  if (threadIdx.x==0){ notI=0; notF=0; anyOdd=0; anyEven=0; }
  __syncthreads();
  int li=0, lf=0, lo=0, le=0;
  for (int i = threadIdx.x; i < 1024; i += 256){
    unsigned int v = w[i];
    if (v != 0u && v != 1u) li = 1;
    if (v != 0u && v != 0x3F800000u) lf = 1;
    if (v != 0u){ if (i & 1) lo = 1; else le = 1; }
  }
  if (li) atomicOr(&notI,1);
  if (lf) atomicOr(&notF,1);
  if (lo) atomicOr(&anyOdd,1);
  if (le) atomicOr(&anyEven,1);
  __syncthreads();
  if (threadIdx.x==0){
    int f;
    if (!notI) f = (anyOdd || !anyEven) ? 0 : 3;
    else       f = (!notF) ? 2 : 1;
    *flag = f;
  }
}

__global__ __launch_bounds__(256) void k_compact(const void* __restrict__ maskp,
    const int* __restrict__ flagp, int* __restrict__ list, int* __restrict__ count){
  __shared__ int cnt[256];
  __shared__ int offs[256];
  int f = *flagp;
  int tid = threadIdx.x;
  int base = tid*16;
  int c = 0;
  for (int i=0;i<16;i++) if (!mask_at(maskp, f, base+i)) c++;
  cnt[tid] = c;
  __syncthreads();
  if (tid==0){
    int r = 0;
    for (int i=0;i<256;i++){ offs[i] = r; r += cnt[i]; }
    *count = r;
  }
  __syncthreads();
  int w = offs[tid];
  for (int i=0;i<16;i++){
    int e = base+i;
    if (!mask_at(maskp, f, e)) list[w++] = e;
  }
}

// ---------------- H = x @ w_in[DEG] (+b_in at j==0), (N,9,128) ----------------
__global__ __launch_bounds__(128) void k_h(const float* __restrict__ x,
    const float* __restrict__ w_in, const float* __restrict__ b_in,
    float* __restrict__ H){
  __shared__ float xl[16][260];
  int i = blockIdx.y; int n0 = blockIdx.x*16;
  int deg = d_DEG[i];
  for (int idx = threadIdx.x; idx < 16*256; idx += 128){
    int r = idx >> 8, c = idx & 255;
    xl[r][c] = x[((size_t)(n0+r)*9 + i)*256 + c];
  }
  __syncthreads();
  int o = threadIdx.x;
  float acc[16];
  #pragma unroll
  for (int r=0;r<16;r++) acc[r]=0.f;
  const float* w = w_in + (size_t)deg*32768 + o;
  for (int c=0;c<256;c+=4){
    float w0=w[(size_t)c*128], w1=w[(size_t)(c+1)*128], w2=w[(size_t)(c+2)*128], w3=w[(size_t)(c+3)*128];
    #pragma unroll
    for (int r=0;r<16;r++){
      float4 xv4 = *(const float4*)&xl[r][c];
      acc[r] += xv4.x*w0 + xv4.y*w1 + xv4.z*w2 + xv4.w*w3;
    }
  }
  float bb = (i==0)? b_in[o] : 0.f;
  #pragma unroll
  for (int r=0;r<16;r++) H[((size_t)(n0+r)*9+i)*128+o] = acc[r]+bb;
}

// ---------------- XE (E,16) ----------------
__global__ __launch_bounds__(256) void k_xe(const float* __restrict__ attn,
    const float* __restrict__ fdw, const float* __restrict__ fdb,
    const float* __restrict__ few, const float* __restrict__ feb,
    const float* __restrict__ es, const float* __restrict__ et,
    const int* __restrict__ an, const int* __restrict__ esrc,
    float* __restrict__ XE){
  int e = blockIdx.x*256 + threadIdx.x;
  float aw[32];
  #pragma unroll
  for (int k=0;k<32;k+=4){
    float4 v = *(const float4*)&attn[(size_t)e*32+k];
    aw[k]=v.x; aw[k+1]=v.y; aw[k+2]=v.z; aw[k+3]=v.w;
  }
  int src = esrc[e]; int tgt = e>>3;
  int za = an[src], zb = an[tgt];
  float v0[16];
  #pragma unroll
  for (int j=0;j<16;j++){
    float s = fdb[j] + es[(size_t)za*16+j] + et[(size_t)zb*16+j];
    #pragma unroll
    for (int k=0;k<32;k++) s += aw[k]*fdw[k*16+j];
    v0[j] = silu_f(s);
  }
  #pragma unroll
  for (int j=0;j<16;j++){
    float s = feb[j];
    #pragma unroll
    for (int k=0;k<16;k++) s += v0[k]*few[k*16+j];
    XE[(size_t)e*16+j] = silu_f(s);
  }
}

// ================= rotate + gates (per edge, dense) =================
__global__ __launch_bounds__(256) void k_rotgate(
    const float* __restrict__ Hg, const float* __restrict__ XEg,
    const int* __restrict__ esrc, const float* __restrict__ wig,
    const float* __restrict__ d0w,  const float* __restrict__ d0b,
    const float* __restrict__ m1dw, const float* __restrict__ m1db,
    const float* __restrict__ m2dw, const float* __restrict__ m2db,
    float* __restrict__ XS, float* __restrict__ XT, float* __restrict__ G,
    int e0)
{
  __shared__ float xe16[16];
  int el = blockIdx.x;
  int e = e0 + el;
  int tid = threadIdx.x;
  int n = e >> 3, src = esrc[e];
  if (tid < 16) xe16[tid] = XEg[(size_t)e*16 + tid];
  for (int idx = tid; idx < 1152; idx += 256){
    int p = idx >> 7, c = idx & 127;
    int ch = d_PERM[p];
    const float* wr = wig + (size_t)e*81 + ch*9;
    const float* hs = Hg + (size_t)src*1152 + c;
    const float* ht = Hg + (size_t)n*1152 + c;
    float s1 = 0.f, s2 = 0.f;
    #pragma unroll
    for (int j = 0; j < 9; j++){
      float wv = wr[j];
      s1 += wv * hs[j*128];
      s2 += wv * ht[j*128];
    }
    XS[(size_t)el*1152 + idx] = s1;
    XT[(size_t)el*1152 + idx] = s2;
  }
  __syncthreads();
  for (int col = tid; col < 1280; col += 256){
    int b = col / 640, r = col % 640;
    const float* w; float bias; int ldw, c2;
    if (r < 128){       w = d0w  + (size_t)b*2048; c2 = r;     ldw = 128; bias = d0b[b*128 + c2]; }
    else if (r < 384){  w = m1dw + (size_t)b*4096; c2 = r-128; ldw = 256; bias = m1db[b*256 + c2]; }
    else {              w = m2dw + (size_t)b*4096; c2 = r-384; ldw = 256; bias = m2db[b*256 + c2]; }
    float s = bias;
    #pragma unroll
    for (int kk = 0; kk < 16; kk++) s += xe16[kk] * w[kk*ldw + c2];
    G[(size_t)el*1280 + col] = silu_f(s);
  }
}

// ================= stage-1 tiled GEMM (all regions in one launch) =================
__global__ __launch_bounds__(256) void k_gs1(
    const float* __restrict__ XS, const float* __restrict__ XT,
    const float* __restrict__ G,
    const float* __restrict__ m0w1,
    const float* __restrict__ m1w1r, const float* __restrict__ m1w1i,
    const float* __restrict__ m2w1r, const float* __restrict__ m2w1i,
    float* __restrict__ Pg)
{
  __shared__ float As[16][68];
  __shared__ float Bs[16][68];
  int b = blockIdx.x;
  int t = threadIdx.x;
  const float* Ax; const float* Bw;
  int K, bm, hbase, obase, goff, rsh, aoff, tstride;
  if (b < 128){
    int mt = b>>2, nt = b&3;
    int path = nt>>1;
    Ax = path ? XT : XS;
    Bw = m0w1 + (size_t)path*49152 + (nt&1)*64;
    K = 384; bm = mt*64; hbase = (nt&1)*64;
    obase = path*128; goff = path ? 640 : 0;
    rsh = 0; aoff = 0; tstride = 0;
  } else if (b < 640){
    int i = b-128; int q = i>>7; int rr = i&127; int mt = rr>>1, nt = rr&1;
    Ax = (q>=2) ? XT : XS;
    Bw = ((q&1) ? m1w1i : m1w1r) + (size_t)((q>=2)?1:0)*32768 + nt*64;
    K = 256; bm = mt*64; hbase = nt*64;
    obase = 256 + q*256; goff = 128 + (q&1)*128 + (q>>1)*640;
    rsh = 1; aoff = 384; tstride = 256;
  } else {
    int i = b-640; int q = i>>7; int rr = i&127; int mt = rr>>1, nt = rr&1;
    Ax = (q>=2) ? XT : XS;
    Bw = ((q&1) ? m2w1i : m2w1r) + (size_t)((q>=2)?1:0)*16384 + nt*64;
    K = 128; bm = mt*64; hbase = nt*64;
    obase = 1280 + q*256; goff = 384 + (q&1)*128 + (q>>1)*640;
    rsh = 1; aoff = 896; tstride = 128;
  }
  int ar = t>>2, ak = (t&3)*4;
  int am = bm + ar;
  int ael = am >> rsh, atp = am & rsh;
  const float* aptr = Ax + (size_t)ael*1152 + aoff + atp*tstride + ak;
  int kb = t>>4, nbb = (t&15)*4;
  const float* bptr = Bw + (size_t)kb*128 + nbb;
  int tx = t&15, ty = t>>4;
  float acc[4][4];
  #pragma unroll
  for (int i2=0;i2<4;i2++){ acc[i2][0]=0.f; acc[i2][1]=0.f; acc[i2][2]=0.f; acc[i2][3]=0.f; }
  for (int k0=0;k0<K;k0+=16){
    float4 av = *(const float4*)(aptr + k0);
    float4 bv = *(const float4*)(bptr + (size_t)k0*128);
    As[ak+0][ar]=av.x; As[ak+1][ar]=av.y; As[ak+2][ar]=av.z; As[ak+3][ar]=av.w;
    *(float4*)&Bs[kb][nbb] = bv;
    __syncthreads();
    #pragma unroll
    for (int k=0;k<16;k++){
      float4 a4 = *(const float4*)&As[k][ty*4];
      float4 b4 = *(const float4*)&Bs[k][tx*4];
      acc[0][0]+=a4.x*b4.x; acc[0][1]+=a4.x*b4.y; acc[0][2]+=a4.x*b4.z; acc[0][3]+=a4.x*b4.w;
      acc[1][0]+=a4.y*b4.x; acc[1][1]+=a4.y*b4.y; acc[1][2]+=a4.y*b4.z; acc[1][3]+=a4.y*b4.w;
      acc[2][0]+=a4.z*b4.x; acc[2][1]+=a4.z*b4.y; acc[2][2]+=a4.z*b4.z; acc[2][3]+=a4.z*b4.w;
      acc[3][0]+=a4.w*b4.x; acc[3][1]+=a4.w*b4.y; acc[3][2]+=a4.w*b4.z; acc[3][3]+=a4.w*b4.w;
    }
    __syncthreads();
  }
  #pragma unroll
  for (int i2=0;i2<4;i2++){
    int m = bm + ty*4 + i2;
    int el = m >> rsh, tp = m & rsh;
    int h = hbase + tx*4;
    float4 gv = *(const float4*)&G[(size_t)el*1280 + goff + h];
    float4 v = make_float4(acc[i2][0]*gv.x, acc[i2][1]*gv.y, acc[i2][2]*gv.z, acc[i2][3]*gv.w);
    *(float4*)&Pg[(size_t)el*2304 + obase + tp*128 + h] = v;
  }
}

// ================= stage-2 tiled GEMM -> Y (orig channel order) =================
__global__ __launch_bounds__(256) void k_gs2(
    const float* __restrict__ Pg,
    const float* __restrict__ m0w2,
    const float* __restrict__ m1w2r, const float* __restrict__ m1w2i,
    const float* __restrict__ m2w2r, const float* __restrict__ m2w2i,
    float* __restrict__ Y)
{
  __shared__ float As[16][68];
  __shared__ float Bs[16][68];
  int b = blockIdx.x;
  int t = threadIdx.x;
  int region, bm, ncolbase, K;
  if (b < 192){ region=0; int mt=b/6, nt=b-mt*6; bm=mt*64; ncolbase=nt*64; K=256; }
  else if (b < 448){ region=1; int i=b-192; int mt=i>>2, nt=i&3; bm=mt*64; ncolbase=nt*64; K=512; }
  else { region=2; int i=b-448; int mt=i>>1, nt=i&1; bm=mt*64; ncolbase=nt*64; K=512; }

  int ar = t>>2, ak = (t&3)*4;
  int am = bm + ar;
  int kb = t>>4, nbb = (t&15)*4;
  int tx = t&15, ty = t>>4;
  float acc[4][4];
  #pragma unroll
  for (int i2=0;i2<4;i2++){ acc[i2][0]=0.f; acc[i2][1]=0.f; acc[i2][2]=0.f; acc[i2][3]=0.f; }

  int ael, atp; float asgn_base;
  if (region==0){ ael = am; atp = 0; asgn_base = 1.f; }
  else { ael = am>>1; atp = am&1; asgn_base = atp ? 1.f : -1.f; }
  int segbase0 = (region==2) ? 1280 : 256;

  for (int k0=0;k0<K;k0+=16){
    float4 av;
    if (region==0){
      av = *(const float4*)(Pg + (size_t)ael*2304 + k0 + ak);
    } else {
      int ks = k0 + ak;
      int seg = ks>>7, kk = ks&127;
      int tsel = (seg&1) ? (1-atp) : atp;
      float sg = (seg&1) ? asgn_base : 1.f;
      av = *(const float4*)(Pg + (size_t)ael*2304 + segbase0 + seg*256 + tsel*128 + kk);
      av.x *= sg; av.y *= sg; av.z *= sg; av.w *= sg;
    }
    float4 bv;
    int ks2 = k0 + kb;
    if (region==0){
      bv = *(const float4*)(m0w2 + (size_t)(ks2>>7)*49152 + (size_t)(ks2&127)*384 + ncolbase + nbb);
    } else if (region==1){
      const float* base = ((ks2>>7)&1) ? m1w2i : m1w2r;
      bv = *(const float4*)(base + (size_t)(ks2>>8)*32768 + (size_t)(ks2&127)*256 + ncolbase + nbb);
    } else {
      const float* base = ((ks2>>7)&1) ? m2w2i : m2w2r;
      bv = *(const float4*)(base + (size_t)(ks2>>8)*16384 + (size_t)(ks2&127)*128 + ncolbase + nbb);
    }
    As[ak+0][ar]=av.x; As[ak+1][ar]=av.y; As[ak+2][ar]=av.z; As[ak+3][ar]=av.w;
    *(float4*)&Bs[kb][nbb] = bv;
    __syncthreads();
    #pragma unroll
    for (int k=0;k<16;k++){
      float4 a4 = *(const float4*)&As[k][ty*4];
      float4 b4 = *(const float4*)&Bs[k][tx*4];
      acc[0][0]+=a4.x*b4.x; acc[0][1]+=a4.x*b4.y; acc[0][2]+=a4.x*b4.z; acc[0][3]+=a4.x*b4.w;
      acc[1][0]+=a4.y*b4.x; acc[1][1]+=a4.y*b4.y; acc[1][2]+=a4.y*b4.z; acc[1][3]+=a4.y*b4.w;
      acc[2][0]+=a4.z*b4.x; acc[2][1]+=a4.z*b4.y; acc[2][2]+=a4.z*b4.z; acc[2][3]+=a4.z*b4.w;
      acc[3][0]+=a4.w*b4.x; acc[3][1]+=a4.w*b4.y; acc[3][2]+=a4.w*b4.z; acc[3][3]+=a4.w*b4.w;
    }
    __syncthreads();
  }
  #pragma unroll
  for (int i2=0;i2<4;i2++){
    int m = bm + ty*4 + i2;
    int el, tp;
    if (region==0){ el = m; tp = 0; } else { el = m>>1; tp = m&1; }
    int col = ncolbase + tx*4;
    int g = col >> 7, c = col & 127;
    int ch;
    if (region==0)      ch = (g==0) ? 0 : ((g==1) ? 2 : 6);
    else if (region==1) ch = tp ? (g ? 5 : 1) : (g ? 7 : 3);
    else                ch = tp ? 4 : 8;
    float4 v = make_float4(acc[i2][0],acc[i2][1],acc[i2][2],acc[i2][3]);
    *(float4*)&Y[(size_t)el*1152 + ch*128 + c] = v;
  }
}

// ================= grid transform over COMPACTED full edge range =================
// 2 active edges/block; LDS coeffs; fused A8; Y/R indexed by ORIGINAL edge id
__global__ __launch_bounds__(256, 4) void k_grid4(const float* __restrict__ Y,
    const float* __restrict__ wig, const float* __restrict__ tg, const float* __restrict__ fg,
    const int* __restrict__ list, const int* __restrict__ countp,
    float* __restrict__ R)
{
  const int cnt = *countp;
  const int base = blockIdx.x*2;
  if (base >= cnt) return;
  __shared__ float cf[324*24];
  __shared__ float wl[2*81];
  int tid = threadIdx.x;
  int e2[2];
  e2[0] = list[base];
  e2[1] = list[(base+1 < cnt) ? base+1 : cnt-1];

  for (int idx = tid; idx < 2916; idx += 256){
    int p = idx / 9, i = idx - p*9;
    cf[p*24 + i]      = tg[idx];
    cf[p*24 + 12 + i] = fg[idx];
  }
  for (int i = tid; i < 162; i += 256){
    int eL2 = i / 81, ii = i - eL2*81;
    wl[i] = wig[(size_t)e2[eL2]*81 + ii];
  }
  __syncthreads();

  int eL = tid >> 7, c = tid & 127;
  int e = e2[eL];

  float y[9], z[9];
  #pragma unroll
  for (int i = 0; i < 9; i++){
    y[i] = Y[(size_t)e*1152 + i*128 + c];
    z[i] = 0.f;
  }

  #pragma unroll 2
  for (int p = 0; p < 324; p++){
    const float* cp = &cf[p*24];
    float4 t0 = *(const float4*)cp;
    float4 t1 = *(const float4*)(cp+4);
    float  t8 = cp[8];
    float gp = t0.x*y[0] + t0.y*y[1] + t0.z*y[2] + t0.w*y[3]
             + t1.x*y[4] + t1.y*y[5] + t1.z*y[6] + t1.w*y[7] + t8*y[8];
    float s = gp * __fdividef(1.0f, 1.0f + __expf(-gp));
    float4 f0 = *(const float4*)(cp+12);
    float4 f1 = *(const float4*)(cp+16);
    float  f8 = cp[20];
    z[0] += f0.x*s; z[1] += f0.y*s; z[2] += f0.z*s; z[3] += f0.w*s;
    z[4] += f1.x*s; z[5] += f1.y*s; z[6] += f1.z*s; z[7] += f1.w*s; z[8] += f8*s;
  }

  const float* wle = &wl[eL*81];
  #pragma unroll
  for (int i2 = 0; i2 < 9; i2++){
    float s = 0.f;
    #pragma unroll
    for (int j = 0; j < 9; j++) s += wle[j*9 + i2] * z[j];
    R[(size_t)e*1152 + i2*128 + c] = s;
  }
}

// ================= masked reduce + w_out projection (full R, global edge idx) =========
__global__ __launch_bounds__(256) void k_redout2(const float* __restrict__ R,
    const void* __restrict__ maskp, const int* __restrict__ flagp,
    const float* __restrict__ w_out, const float* __restrict__ b_out,
    float* __restrict__ out){
  __shared__ float sacc[128];
  int i2 = blockIdx.x; int n = blockIdx.y;
  int tid = threadIdx.x;
  int f = *flagp;
  if (tid < 128){
    float a = 0.f;
    for (int k = 0; k < 8; k++){
      int e = n*8 + k;
      if (!mask_at(maskp, f, e)) a += R[(size_t)e*1152 + i2*128 + tid];
    }
    sacc[tid] = a;
  }
  __syncthreads();
  int o = tid;
  int deg = d_DEG[i2];
  const float* wp = w_out + (size_t)deg*32768 + o;
  float s = (i2==0) ? b_out[o] : 0.f;
  #pragma unroll 4
  for (int c = 0; c < 128; c += 4){
    float4 a = *(const float4*)&sacc[c];
    s += a.x*wp[(size_t)c*256] + a.y*wp[(size_t)(c+1)*256]
       + a.z*wp[(size_t)(c+2)*256] + a.w*wp[(size_t)(c+3)*256];
  }
  out[((size_t)n*9 + i2)*256 + o] = s;
}

// ================= tier-2 kernels (round-10 proven path) =================
__global__ __launch_bounds__(256, 4) void k_grid3(const float* __restrict__ Y,
    const float* __restrict__ wig, const float* __restrict__ tg, const float* __restrict__ fg,
    const void* __restrict__ maskp, const int* __restrict__ flagp,
    float* __restrict__ R, int e0)
{
  __shared__ float cf[324*24];
  __shared__ float wl[2*81];
  int tid = threadIdx.x;
  int el0 = blockIdx.x*2;
  for (int idx = tid; idx < 2916; idx += 256){
    int p = idx / 9, i = idx - p*9;
    cf[p*24 + i]      = tg[idx];
    cf[p*24 + 12 + i] = fg[idx];
  }
  for (int i = tid; i < 162; i += 256){
    int eL2 = i / 81, ii = i - eL2*81;
    wl[i] = wig[(size_t)(e0 + el0 + eL2)*81 + ii];
  }
  __syncthreads();
  int eL = tid >> 7, c = tid & 127;
  int el = el0 + eL;
  int e = e0 + el;
  if (mask_at(maskp, *flagp, e)) return;
  float y[9], z[9];
  #pragma unroll
  for (int i = 0; i < 9; i++){
    y[i] = Y[(size_t)el*1152 + i*128 + c];
    z[i] = 0.f;
  }
  #pragma unroll 2
  for (int p = 0; p < 324; p++){
    const float* cp = &cf[p*24];
    float4 t0 = *(const float4*)cp;
    float4 t1 = *(const float4*)(cp+4);
    float  t8 = cp[8];
    float gp = t0.x*y[0] + t0.y*y[1] + t0.z*y[2] + t0.w*y[3]
             + t1.x*y[4] + t1.y*y[5] + t1.z*y[6] + t1.w*y[7] + t8*y[8];
    float s = gp * __fdividef(1.0f, 1.0f + __expf(-gp));
    float4 f0 = *(const float4*)(cp+12);
    float4 f1 = *(const float4*)(cp+16);
    float  f8 = cp[20];
    z[0] += f0.x*s; z[1] += f0.y*s; z[2] += f0.z*s; z[3] += f0.w*s;
    z[4] += f1.x*s; z[5] += f1.y*s; z[6] += f1.z*s; z[7] += f1.w*s; z[8] += f8*s;
  }
  const float* wle = &wl[eL*81];
  #pragma unroll
  for (int i2 = 0; i2 < 9; i2++){
    float s = 0.f;
    #pragma unroll
    for (int j = 0; j < 9; j++) s += wle[j*9 + i2] * z[j];
    R[(size_t)el*1152 + i2*128 + c] = s;
  }
}

__global__ __launch_bounds__(256) void k_redout(const float* __restrict__ R,
    const void* __restrict__ maskp, const int* __restrict__ flagp,
    const float* __restrict__ w_out, const float* __restrict__ b_out,
    float* __restrict__ out, int n0){
  __shared__ float sacc[128];
  int i2 = blockIdx.x; int nl = blockIdx.y;
  int n = n0 + nl;
  int tid = threadIdx.x;
  int f = *flagp;
  if (tid < 128){
    float a = 0.f;
    for (int k = 0; k < 8; k++){
      int e = n*8 + k;
      if (!mask_at(maskp, f, e)) a += R[(size_t)(nl*8+k)*1152 + i2*128 + tid];
    }
    sacc[tid] = a;
  }
  __syncthreads();
  int o = tid;
  int deg = d_DEG[i2];
  const float* wp = w_out + (size_t)deg*32768 + o;
  float s = (i2==0) ? b_out[o] : 0.f;
  #pragma unroll 4
  for (int c = 0; c < 128; c += 4){
    float4 a = *(const float4*)&sacc[c];
    s += a.x*wp[(size_t)c*256] + a.y*wp[(size_t)(c+1)*256]
       + a.z*wp[(size_t)(c+2)*256] + a.w*wp[(size_t)(c+3)*256];
  }
  out[((size_t)n*9 + i2)*256 + o] = s;
}

// ================= tier-3 fallback mega kernel (round-5, pass-verified) =================
__device__ __forceinline__ float dotW(const float* __restrict__ A, const float* __restrict__ Wm, int K){
  float s = 0.f;
  #pragma unroll 4
  for (int i=0;i<K;i+=4){
    float4 a = *(const float4*)&A[i];
    s += a.x*Wm[(size_t)i*128] + a.y*Wm[(size_t)(i+1)*128]
       + a.z*Wm[(size_t)(i+2)*128] + a.w*Wm[(size_t)(i+3)*128];
  }
  return s;
}
__device__ __forceinline__ float dot2W(const float* __restrict__ P0, const float* __restrict__ P1,
    const float* __restrict__ W0, const float* __restrict__ W1, int ldw){
  float s = 0.f;
  #pragma unroll 4
  for (int k=0;k<128;k+=4){
    float4 a = *(const float4*)&P0[k];
    float4 b = *(const float4*)&P1[k];
    s += a.x*W0[(size_t)k*ldw] + a.y*W0[(size_t)(k+1)*ldw] + a.z*W0[(size_t)(k+2)*ldw] + a.w*W0[(size_t)(k+3)*ldw];
    s += b.x*W1[(size_t)k*ldw] + b.y*W1[(size_t)(k+1)*ldw] + b.z*W1[(size_t)(k+2)*ldw] + b.w*W1[(size_t)(k+3)*ldw];
  }
  return s;
}

__global__ __launch_bounds__(256) void k_mega(
    const float* __restrict__ x,      const float* __restrict__ w_in,  const float* __restrict__ b_in,
    const float* __restrict__ attn,
    const float* __restrict__ fdw,    const float* __restrict__ fdb,
    const float* __restrict__ few,    const float* __restrict__ feb,
    const float* __restrict__ es,     const float* __restrict__ et,
    const int*   __restrict__ an,     const int*   __restrict__ esrc,
    const float* __restrict__ d0w,    const float* __restrict__ d0b,
    const float* __restrict__ m1dw,   const float* __restrict__ m1db,
    const float* __restrict__ m2dw,   const float* __restrict__ m2db,
    const float* __restrict__ m0w1,   const float* __restrict__ m0w2,
    const float* __restrict__ m1w1r,  const float* __restrict__ m1w2r,
    const float* __restrict__ m1w1i,  const float* __restrict__ m1w2i,
    const float* __restrict__ m2w1r,  const float* __restrict__ m2w2r,
    const float* __restrict__ m2w1i,  const float* __restrict__ m2w2i,
    const float* __restrict__ wig,    const float* __restrict__ tg,   const float* __restrict__ fg,
    const float* __restrict__ w_out,  const float* __restrict__ b_out,
    const void*  __restrict__ maskp,  const int* __restrict__ flagp,
    float* __restrict__ out)
{
  __shared__ float S[7168];
  float* acc  = S;
  float* xs   = S + 1152;
  float* xtl  = S + 2304;
  float* Zb   = S + 1152;
  float* gg   = S + 3456;
  float* Yb   = S + 3456;
  float* P    = S + 4736;
  float* wl   = S + 7040;
  float* xe16 = S + 7124;
  float* xv   = S + 7140;

  const int n   = blockIdx.x;
  const int tid = threadIdx.x;
  const int f   = *flagp;

  for (int i = tid; i < 1152; i += 256) acc[i] = 0.f;

  for (int k = 0; k < 8; k++){
    int e = n*8 + k;
    if (mask_at(maskp, f, e)) continue;
    int src = esrc[e];
    __syncthreads();
    for (int i = tid; i < 81; i += 256) wl[i] = wig[(size_t)e*81 + i];
    if (tid < 16){
      int j = tid;
      float s = fdb[j] + es[(size_t)an[src]*16 + j] + et[(size_t)an[n]*16 + j];
      for (int kk = 0; kk < 32; kk++) s += attn[(size_t)e*32 + kk] * fdw[kk*16 + j];
      xv[j] = silu_f(s);
    }
    for (int idx = tid; idx < 2304; idx += 256){
      int which = idx >= 1152;
      int lidx = idx - which*1152;
      int j = lidx >> 7, c = lidx & 127;
      int deg = d_DEG[j];
      const float* wp = w_in + (size_t)deg*32768 + c;
      const float* xp = x + ((size_t)(which ? n : src)*9 + j)*256;
      float s = (j==0) ? b_in[c] : 0.f;
      for (int cc = 0; cc < 256; cc++) s += xp[cc] * wp[cc*128];
      P[idx] = s;
    }
    __syncthreads();
    if (tid < 16){
      int j = tid;
      float s = feb[j];
      for (int kk = 0; kk < 16; kk++) s += xv[kk] * few[kk*16 + j];
      xe16[j] = silu_f(s);
    }
    for (int idx = tid; idx < 1152; idx += 256){
      int p = idx >> 7, c = idx & 127;
      int ch = d_PERM[p];
      float s1 = 0.f, s2 = 0.f;
      #pragma unroll
      for (int j = 0; j < 9; j++){
        float wv = wl[ch*9 + j];
        s1 += wv * P[j*128 + c];
        s2 += wv * P[1152 + j*128 + c];
      }
      xs[idx]  = s1;
      xtl[idx] = s2;
    }
    __syncthreads();
    for (int col = tid; col < 1280; col += 256){
      int b = col / 640, r = col % 640;
      const float* w; float bias; int ldw, c2;
      if (r < 128){       w = d0w  + (size_t)b*2048; c2 = r;     ldw = 128; bias = d0b[b*128 + c2]; }
      else if (r < 384){  w = m1dw + (size_t)b*4096; c2 = r-128; ldw = 256; bias = m1db[b*256 + c2]; }
      else {              w = m2dw + (size_t)b*4096; c2 = r-384; ldw = 256; bias = m2db[b*256 + c2]; }
      float s = bias;
      #pragma unroll
      for (int kk = 0; kk < 16; kk++) s += xe16[kk] * w[kk*ldw + c2];
      gg[col] = silu_f(s);
    }
    __syncthreads();
    for (int o = tid; o < 2304; o += 256){
      float s;
      if (o < 256){
        int path = o >> 7, h = o & 127;
        s = dotW(path ? xtl : xs, m0w1 + (size_t)path*49152 + h, 384);
      } else if (o < 1280){
        int q = (o-256) >> 8; int rem = (o-256) & 255; int t = rem >> 7, h = rem & 127;
        const float* A  = ((q>=2) ? xtl : xs) + 384 + t*256;
        const float* Wm = ((q&1) ? m1w1i : m1w1r) + (size_t)((q>=2)?1:0)*32768 + h;
        s = dotW(A, Wm, 256);
      } else {
        int q = (o-1280) >> 8; int rem = (o-1280) & 255; int t = rem >> 7, h = rem & 127;
        const float* A  = ((q>=2) ? xtl : xs) + 896 + t*128;
        const float* Wm = ((q&1) ? m2w1i : m2w1r) + (size_t)((q>=2)?1:0)*16384 + h;
        s = dotW(A, Wm, 128);
      }
      P[o] = s;
    }
    __syncthreads();
    for (int o = tid; o < 2304; o += 256){
      int h = o & 127, goff;
      if (o < 256) goff = (o >> 7) ? 640 : 0;
      else if (o < 1280){ int q = (o-256) >> 8;  goff = 128 + (q&1)*128 + (q>>1)*640; }
      else              { int q = (o-1280) >> 8; goff = 384 + (q&1)*128 + (q>>1)*640; }
      P[o] *= gg[goff + h];
    }
    __syncthreads();
    for (int o = tid; o < 1152; o += 256){
      float s; int ch, c;
      if (o < 384){
        int g = o >> 7; c = o & 127;
        ch = (g==0) ? 0 : ((g==1) ? 2 : 6);
        const float* w0 = m0w2 + o;
        s = dot2W(P, P+128, w0, w0+49152, 384);
      } else if (o < 896){
        int om = o - 384; int tp = om >> 8; int col = om & 255;
        int g = col >> 7; c = col & 127;
        ch = tp ? (g ? 5 : 1) : (g ? 7 : 3);
        float sgn = tp ? 1.f : -1.f;
        const float* wr = m1w2r + col;
        const float* wi = m1w2i + col;
        s = dot2W(P+256+tp*128,     P+768+tp*128,     wr, wr+32768, 256)
          + sgn * dot2W(P+512+(1-tp)*128, P+1024+(1-tp)*128, wi, wi+32768, 256);
      } else {
        int om = o - 896; int tp = om >> 7; c = om & 127;
        ch = tp ? 4 : 8;
        float sgn = tp ? 1.f : -1.f;
        const float* wr = m2w2r + c;
        const float* wi = m2w2i + c;
        s = dot2W(P+1280+tp*128,     P+1792+tp*128,     wr, wr+16384, 128)
          + sgn * dot2W(P+1536+(1-tp)*128, P+2048+(1-tp)*128, wi, wi+16384, 128);
      }
      Yb[ch*128 + c] = s;
    }
    __syncthreads();
    {
      int half = tid >> 7, c = tid & 127;
      float z[9];
      #pragma unroll
      for (int i = 0; i < 9; i++) z[i] = 0.f;
      float y[9];
      #pragma unroll
      for (int i = 0; i < 9; i++) y[i] = Yb[i*128 + c];
      int p0 = half*162, p1 = p0 + 162;
      #pragma unroll 2
      for (int p = p0; p < p1; p++){
        float gp = 0.f;
        #pragma unroll
        for (int i = 0; i < 9; i++) gp += tg[p*9 + i] * y[i];
        float s = silu_f(gp);
        #pragma unroll
        for (int i = 0; i < 9; i++) z[i] += fg[p*9 + i] * s;
      }
      #pragma unroll
      for (int i = 0; i < 9; i++) Zb[half*1152 + i*128 + c] = z[i];
    }
    __syncthreads();
    for (int idx = tid; idx < 1152; idx += 256){
      int i2 = idx >> 7, c = idx & 127;
      float s = 0.f;
      #pragma unroll
      for (int j = 0; j < 9; j++)
        s += wl[j*9 + i2] * (Zb[j*128 + c] + Zb[1152 + j*128 + c]);
      acc[idx] += s;
    }
  }
  __syncthreads();
  {
    int o = tid;
    for (int i2 = 0; i2 < 9; i2++){
      int deg = d_DEG[i2];
      const float* wp = w_out + (size_t)deg*32768 + o;
      float s = (i2==0) ? b_out[o] : 0.f;
      #pragma unroll 4
      for (int c = 0; c < 128; c += 4){
        float4 a = *(const float4*)&acc[i2*128 + c];
        s += a.x*wp[(size_t)c*256] + a.y*wp[(size_t)(c+1)*256]
           + a.z*wp[(size_t)(c+2)*256] + a.w*wp[(size_t)(c+3)*256];
      }
      out[((size_t)n*9 + i2)*256 + o] = s;
    }
  }
}

// ---------------- host ----------------
extern "C" void kernel_launch(void* const* d_in, const int* in_sizes, int n_in,
                              void* d_out, int out_size, void* d_ws, size_t ws_size,
                              hipStream_t stream){
  const float* x     = (const float*)d_in[0];
  const float* attn  = (const float*)d_in[1];
  const float* wig   = (const float*)d_in[2];
  const float* tg    = (const float*)d_in[3];
  const float* fg    = (const float*)d_in[4];
  const float* w_in  = (const float*)d_in[5];
  const float* b_in  = (const float*)d_in[6];
  const float* w_out = (const float*)d_in[7];
  const float* b_out = (const float*)d_in[8];
  const float* es    = (const float*)d_in[9];
  const float* et    = (const float*)d_in[10];
  const float* fdw   = (const float*)d_in[11];
  const float* fdb   = (const float*)d_in[12];
  const float* few   = (const float*)d_in[13];
  const float* feb   = (const float*)d_in[14];
  const float* d0w   = (const float*)d_in[15];
  const float* d0b   = (const float*)d_in[16];
  const float* m0w1  = (const float*)d_in[17];
  const float* m0w2  = (const float*)d_in[18];
  const float* m1dw  = (const float*)d_in[19];
  const float* m1db  = (const float*)d_in[20];
  const float* m1w1r = (const float*)d_in[21];
  const float* m1w2r = (const float*)d_in[22];
  const float* m1w1i = (const float*)d_in[23];
  const float* m1w2i = (const float*)d_in[24];
  const float* m2dw  = (const float*)d_in[25];
  const float* m2db  = (const float*)d_in[26];
  const float* m2w1r = (const float*)d_in[27];
  const float* m2w2r = (const float*)d_in[28];
  const float* m2w1i = (const float*)d_in[29];
  const float* m2w2i = (const float*)d_in[30];
  const int*   an    = (const int*)d_in[31];
  const int*   esrc  = (const int*)d_in[32];
  const void*  maskp = d_in[33];

  // ---- tier-1 layout (compaction + full-range grid) ----
  int*   ip  = (int*)d_ws;
  int* FLAG  = ip + 0;
  int* COUNT = ip + 1;
  int* LIST  = ip + 16;                 // 4096 ints, ends at int offset 4112
  float* W   = (float*)d_ws;
  float* Hg1  = W + 4112;               // 589824
  float* XEg1 = Hg1 + 589824;           // 65536
  float* XS1  = XEg1 + 65536;           // 2359296 (2048*1152)
  float* XT1  = XS1 + 2359296;          // 2359296
  float* Gg1  = XT1 + 2359296;          // 2621440 (2048*1280)
  float* Pg1  = Gg1 + 2621440;          // 4718592 (2048*2304)
  float* Yf   = Pg1 + 4718592;          // 4718592 (4096*1152) full
  float* Rf   = XS1;                    // alias XS1+XT1 (4718592) after both chunks' gs1 done
  size_t need_t1 = (size_t)(4112 + 589824 + 65536 + 2359296 + 2359296 + 2621440 + 4718592 + 4718592) * 4;

  // ---- tier-2 layout (round-10 exact, proven 437us) ----
  float* Hg2  = W + 16;
  float* XEg2 = W + 589840;
  float* XS2  = W + 655376;
  float* XT2  = W + 3014672;
  float* Gg2  = W + 5373968;
  float* Pg2  = W + 7995408;
  float* Yc2  = XS2;
  float* Rc2  = XT2;
  size_t need_t2 = (size_t)12714000 * 4;

  k_detect<<<1,256,0,stream>>>((const unsigned int*)maskp, FLAG);

  if (ws_size >= need_t1){
    k_compact<<<1,256,0,stream>>>(maskp, FLAG, LIST, COUNT);
    k_h<<<dim3(32,9),128,0,stream>>>(x, w_in, b_in, Hg1);
    k_xe<<<16,256,0,stream>>>(attn, fdw, fdb, few, feb, es, et, an, esrc, XEg1);
    for (int c2 = 0; c2 < 2; c2++){
      int e0 = c2*2048;
      k_rotgate<<<2048,256,0,stream>>>(Hg1, XEg1, esrc, wig,
          d0w, d0b, m1dw, m1db, m2dw, m2db, XS1, XT1, Gg1, e0);
      k_gs1<<<1152,256,0,stream>>>(XS1, XT1, Gg1,
          m0w1, m1w1r, m1w1i, m2w1r, m2w1i, Pg1);
      k_gs2<<<576,256,0,stream>>>(Pg1, m0w2, m1w2r, m1w2i, m2w2r, m2w2i,
          Yf + (size_t)e0*1152);
    }
    k_grid4<<<2048,256,0,stream>>>(Yf, wig, tg, fg, LIST, COUNT, Rf);
    k_redout2<<<dim3(9,512),256,0,stream>>>(Rf, maskp, FLAG, w_out, b_out, (float*)d_out);
  } else if (ws_size >= need_t2){
    k_h<<<dim3(32,9),128,0,stream>>>(x, w_in, b_in, Hg2);
    k_xe<<<16,256,0,stream>>>(attn, fdw, fdb, few, feb, es, et, an, esrc, XEg2);
    for (int c2 = 0; c2 < 2; c2++){
      int e0 = c2*2048, n0 = c2*256;
      k_rotgate<<<2048,256,0,stream>>>(Hg2, XEg2, esrc, wig,
          d0w, d0b, m1dw, m1db, m2dw, m2db, XS2, XT2, Gg2, e0);
      k_gs1<<<1152,256,0,stream>>>(XS2, XT2, Gg2,
          m0w1, m1w1r, m1w1i, m2w1r, m2w1i, Pg2);
      k_gs2<<<576,256,0,stream>>>(Pg2, m0w2, m1w2r, m1w2i, m2w2r, m2w2i, Yc2);
      k_grid3<<<1024,256,0,stream>>>(Yc2, wig, tg, fg, maskp, FLAG, Rc2, e0);
      k_redout<<<dim3(9,256),256,0,stream>>>(Rc2, maskp, FLAG, w_out, b_out, (float*)d_out, n0);
    }
  } else {
    k_mega<<<512,256,0,stream>>>(
        x, w_in, b_in, attn, fdw, fdb, few, feb, es, et, an, esrc,
        d0w, d0b, m1dw, m1db, m2dw, m2db,
        m0w1, m0w2, m1w1r, m1w2r, m1w1i, m1w2i, m2w1r, m2w2r, m2w1i, m2w2i,
        wig, tg, fg, w_out, b_out, maskp, FLAG, (float*)d_out);
  }
}

// Round 12
// 353.385 us; speedup vs baseline: 1.6339x; 1.0490x over previous
//
#include <hip/hip_runtime.h>
#include <math.h>

__device__ const int d_PERM[9] = {0,2,6,3,7,1,5,8,4};
__device__ const int d_DEG[9]  = {0,1,1,1,2,2,2,2,2};

__device__ __forceinline__ float silu_f(float x){ return x / (1.0f + __expf(-x)); }

// flag: 0 = int32 words, 1 = u8 bytes, 2 = float32 words, 3 = int64 (low word)
__device__ __forceinline__ int mask_at(const void* mp, int flag, int e){
  if (flag==1) return ((const unsigned char*)mp)[e] != 0;
  if (flag==3) return ((const unsigned int*)mp)[2*e] != 0u;
  return ((const unsigned int*)mp)[e] != 0u;
}

__global__ void k_detect(const unsigned int* __restrict__ w, int* __restrict__ flag){
  __shared__ int notI, notF, anyOdd, anyEven;
  if (threadIdx.x==0){ notI=0; notF=0; anyOdd=0; anyEven=0; }
  __syncthreads();
  int li=0, lf=0, lo=0, le=0;
  for (int i = threadIdx.x; i < 1024; i += 256){
    unsigned int v = w[i];
    if (v != 0u && v != 1u) li = 1;
    if (v != 0u && v != 0x3F800000u) lf = 1;
    if (v != 0u){ if (i & 1) lo = 1; else le = 1; }
  }
  if (li) atomicOr(&notI,1);
  if (lf) atomicOr(&notF,1);
  if (lo) atomicOr(&anyOdd,1);
  if (le) atomicOr(&anyEven,1);
  __syncthreads();
  if (threadIdx.x==0){
    int f;
    if (!notI) f = (anyOdd || !anyEven) ? 0 : 3;
    else       f = (!notF) ? 2 : 1;
    *flag = f;
  }
}

__global__ __launch_bounds__(256) void k_compact(const void* __restrict__ maskp,
    const int* __restrict__ flagp, int* __restrict__ list, int* __restrict__ count){
  __shared__ int cnt[256];
  __shared__ int offs[256];
  int f = *flagp;
  int tid = threadIdx.x;
  int base = tid*16;
  int c = 0;
  for (int i=0;i<16;i++) if (!mask_at(maskp, f, base+i)) c++;
  cnt[tid] = c;
  __syncthreads();
  if (tid==0){
    int r = 0;
    for (int i=0;i<256;i++){ offs[i] = r; r += cnt[i]; }
    *count = r;
  }
  __syncthreads();
  int w = offs[tid];
  for (int i=0;i<16;i++){
    int e = base+i;
    if (!mask_at(maskp, f, e)) list[w++] = e;
  }
}

// ---------------- H = x @ w_in[DEG] (+b_in at j==0), (N,9,128) ----------------
__global__ __launch_bounds__(128) void k_h(const float* __restrict__ x,
    const float* __restrict__ w_in, const float* __restrict__ b_in,
    float* __restrict__ H){
  __shared__ float xl[16][260];
  int i = blockIdx.y; int n0 = blockIdx.x*16;
  int deg = d_DEG[i];
  for (int idx = threadIdx.x; idx < 16*256; idx += 128){
    int r = idx >> 8, c = idx & 255;
    xl[r][c] = x[((size_t)(n0+r)*9 + i)*256 + c];
  }
  __syncthreads();
  int o = threadIdx.x;
  float acc[16];
  #pragma unroll
  for (int r=0;r<16;r++) acc[r]=0.f;
  const float* w = w_in + (size_t)deg*32768 + o;
  for (int c=0;c<256;c+=4){
    float w0=w[(size_t)c*128], w1=w[(size_t)(c+1)*128], w2=w[(size_t)(c+2)*128], w3=w[(size_t)(c+3)*128];
    #pragma unroll
    for (int r=0;r<16;r++){
      float4 xv4 = *(const float4*)&xl[r][c];
      acc[r] += xv4.x*w0 + xv4.y*w1 + xv4.z*w2 + xv4.w*w3;
    }
  }
  float bb = (i==0)? b_in[o] : 0.f;
  #pragma unroll
  for (int r=0;r<16;r++) H[((size_t)(n0+r)*9+i)*128+o] = acc[r]+bb;
}

// ---------------- XE (E,16) ----------------
__global__ __launch_bounds__(256) void k_xe(const float* __restrict__ attn,
    const float* __restrict__ fdw, const float* __restrict__ fdb,
    const float* __restrict__ few, const float* __restrict__ feb,
    const float* __restrict__ es, const float* __restrict__ et,
    const int* __restrict__ an, const int* __restrict__ esrc,
    float* __restrict__ XE){
  int e = blockIdx.x*256 + threadIdx.x;
  float aw[32];
  #pragma unroll
  for (int k=0;k<32;k+=4){
    float4 v = *(const float4*)&attn[(size_t)e*32+k];
    aw[k]=v.x; aw[k+1]=v.y; aw[k+2]=v.z; aw[k+3]=v.w;
  }
  int src = esrc[e]; int tgt = e>>3;
  int za = an[src], zb = an[tgt];
  float v0[16];
  #pragma unroll
  for (int j=0;j<16;j++){
    float s = fdb[j] + es[(size_t)za*16+j] + et[(size_t)zb*16+j];
    #pragma unroll
    for (int k=0;k<32;k++) s += aw[k]*fdw[k*16+j];
    v0[j] = silu_f(s);
  }
  #pragma unroll
  for (int j=0;j<16;j++){
    float s = feb[j];
    #pragma unroll
    for (int k=0;k<16;k++) s += v0[k]*few[k*16+j];
    XE[(size_t)e*16+j] = silu_f(s);
  }
}

// ================= rotate + gates over COMPACTED slots =================
__global__ __launch_bounds__(256) void k_rotgate_c(
    const float* __restrict__ Hg, const float* __restrict__ XEg,
    const int* __restrict__ esrc, const float* __restrict__ wig,
    const float* __restrict__ d0w,  const float* __restrict__ d0b,
    const float* __restrict__ m1dw, const float* __restrict__ m1db,
    const float* __restrict__ m2dw, const float* __restrict__ m2db,
    float* __restrict__ XS, float* __restrict__ XT, float* __restrict__ G,
    const int* __restrict__ list, const int* __restrict__ countp, int s0)
{
  int slot = s0 + blockIdx.x;
  if (slot >= *countp) return;
  __shared__ float xe16[16];
  int e = list[slot];
  int el = blockIdx.x;           // local slot index within chunk
  int tid = threadIdx.x;
  int n = e >> 3, src = esrc[e];
  if (tid < 16) xe16[tid] = XEg[(size_t)e*16 + tid];
  for (int idx = tid; idx < 1152; idx += 256){
    int p = idx >> 7, c = idx & 127;
    int ch = d_PERM[p];
    const float* wr = wig + (size_t)e*81 + ch*9;
    const float* hs = Hg + (size_t)src*1152 + c;
    const float* ht = Hg + (size_t)n*1152 + c;
    float s1 = 0.f, s2 = 0.f;
    #pragma unroll
    for (int j = 0; j < 9; j++){
      float wv = wr[j];
      s1 += wv * hs[j*128];
      s2 += wv * ht[j*128];
    }
    XS[(size_t)el*1152 + idx] = s1;
    XT[(size_t)el*1152 + idx] = s2;
  }
  __syncthreads();
  for (int col = tid; col < 1280; col += 256){
    int b = col / 640, r = col % 640;
    const float* w; float bias; int ldw, c2;
    if (r < 128){       w = d0w  + (size_t)b*2048; c2 = r;     ldw = 128; bias = d0b[b*128 + c2]; }
    else if (r < 384){  w = m1dw + (size_t)b*4096; c2 = r-128; ldw = 256; bias = m1db[b*256 + c2]; }
    else {              w = m2dw + (size_t)b*4096; c2 = r-384; ldw = 256; bias = m2db[b*256 + c2]; }
    float s = bias;
    #pragma unroll
    for (int kk = 0; kk < 16; kk++) s += xe16[kk] * w[kk*ldw + c2];
    G[(size_t)el*1280 + col] = silu_f(s);
  }
}

// ================= stage-1 tiled GEMM over compacted rows =================
__global__ __launch_bounds__(256) void k_gs1(
    const float* __restrict__ XS, const float* __restrict__ XT,
    const float* __restrict__ G,
    const float* __restrict__ m0w1,
    const float* __restrict__ m1w1r, const float* __restrict__ m1w1i,
    const float* __restrict__ m2w1r, const float* __restrict__ m2w1i,
    float* __restrict__ Pg,
    const int* __restrict__ countp, int s0)
{
  int lc = *countp - s0;
  if (lc <= 0) return;
  if (lc > 2048) lc = 2048;
  __shared__ float As[16][68];
  __shared__ float Bs[16][68];
  int b = blockIdx.x;
  int t = threadIdx.x;
  const float* Ax; const float* Bw;
  int K, bm, hbase, obase, goff, rsh, aoff, tstride;
  if (b < 128){
    int mt = b>>2, nt = b&3;
    int path = nt>>1;
    Ax = path ? XT : XS;
    Bw = m0w1 + (size_t)path*49152 + (nt&1)*64;
    K = 384; bm = mt*64; hbase = (nt&1)*64;
    obase = path*128; goff = path ? 640 : 0;
    rsh = 0; aoff = 0; tstride = 0;
  } else if (b < 640){
    int i = b-128; int q = i>>7; int rr = i&127; int mt = rr>>1, nt = rr&1;
    Ax = (q>=2) ? XT : XS;
    Bw = ((q&1) ? m1w1i : m1w1r) + (size_t)((q>=2)?1:0)*32768 + nt*64;
    K = 256; bm = mt*64; hbase = nt*64;
    obase = 256 + q*256; goff = 128 + (q&1)*128 + (q>>1)*640;
    rsh = 1; aoff = 384; tstride = 256;
  } else {
    int i = b-640; int q = i>>7; int rr = i&127; int mt = rr>>1, nt = rr&1;
    Ax = (q>=2) ? XT : XS;
    Bw = ((q&1) ? m2w1i : m2w1r) + (size_t)((q>=2)?1:0)*16384 + nt*64;
    K = 128; bm = mt*64; hbase = nt*64;
    obase = 1280 + q*256; goff = 384 + (q&1)*128 + (q>>1)*640;
    rsh = 1; aoff = 896; tstride = 128;
  }
  int rows = (rsh ? 2*lc : lc);
  if (bm >= rows) return;
  int ar = t>>2, ak = (t&3)*4;
  int am = bm + ar;
  int ael = am >> rsh, atp = am & rsh;
  const float* aptr = Ax + (size_t)ael*1152 + aoff + atp*tstride + ak;
  int kb = t>>4, nbb = (t&15)*4;
  const float* bptr = Bw + (size_t)kb*128 + nbb;
  int tx = t&15, ty = t>>4;
  float acc[4][4];
  #pragma unroll
  for (int i2=0;i2<4;i2++){ acc[i2][0]=0.f; acc[i2][1]=0.f; acc[i2][2]=0.f; acc[i2][3]=0.f; }
  for (int k0=0;k0<K;k0+=16){
    float4 av = *(const float4*)(aptr + k0);
    float4 bv = *(const float4*)(bptr + (size_t)k0*128);
    As[ak+0][ar]=av.x; As[ak+1][ar]=av.y; As[ak+2][ar]=av.z; As[ak+3][ar]=av.w;
    *(float4*)&Bs[kb][nbb] = bv;
    __syncthreads();
    #pragma unroll
    for (int k=0;k<16;k++){
      float4 a4 = *(const float4*)&As[k][ty*4];
      float4 b4 = *(const float4*)&Bs[k][tx*4];
      acc[0][0]+=a4.x*b4.x; acc[0][1]+=a4.x*b4.y; acc[0][2]+=a4.x*b4.z; acc[0][3]+=a4.x*b4.w;
      acc[1][0]+=a4.y*b4.x; acc[1][1]+=a4.y*b4.y; acc[1][2]+=a4.y*b4.z; acc[1][3]+=a4.y*b4.w;
      acc[2][0]+=a4.z*b4.x; acc[2][1]+=a4.z*b4.y; acc[2][2]+=a4.z*b4.z; acc[2][3]+=a4.z*b4.w;
      acc[3][0]+=a4.w*b4.x; acc[3][1]+=a4.w*b4.y; acc[3][2]+=a4.w*b4.z; acc[3][3]+=a4.w*b4.w;
    }
    __syncthreads();
  }
  #pragma unroll
  for (int i2=0;i2<4;i2++){
    int m = bm + ty*4 + i2;
    int el = m >> rsh, tp = m & rsh;
    int h = hbase + tx*4;
    float4 gv = *(const float4*)&G[(size_t)el*1280 + goff + h];
    float4 v = make_float4(acc[i2][0]*gv.x, acc[i2][1]*gv.y, acc[i2][2]*gv.z, acc[i2][3]*gv.w);
    *(float4*)&Pg[(size_t)el*2304 + obase + tp*128 + h] = v;
  }
}

// ================= stage-2 tiled GEMM -> Y (by GLOBAL slot) =================
__global__ __launch_bounds__(256) void k_gs2(
    const float* __restrict__ Pg,
    const float* __restrict__ m0w2,
    const float* __restrict__ m1w2r, const float* __restrict__ m1w2i,
    const float* __restrict__ m2w2r, const float* __restrict__ m2w2i,
    float* __restrict__ Y,
    const int* __restrict__ countp, int s0)
{
  int lc = *countp - s0;
  if (lc <= 0) return;
  if (lc > 2048) lc = 2048;
  __shared__ float As[16][68];
  __shared__ float Bs[16][68];
  int b = blockIdx.x;
  int t = threadIdx.x;
  int region, bm, ncolbase, K;
  if (b < 192){ region=0; int mt=b/6, nt=b-mt*6; bm=mt*64; ncolbase=nt*64; K=256; }
  else if (b < 448){ region=1; int i=b-192; int mt=i>>2, nt=i&3; bm=mt*64; ncolbase=nt*64; K=512; }
  else { region=2; int i=b-448; int mt=i>>1, nt=i&1; bm=mt*64; ncolbase=nt*64; K=512; }
  int rows = (region==0) ? lc : 2*lc;
  if (bm >= rows) return;

  int ar = t>>2, ak = (t&3)*4;
  int am = bm + ar;
  int kb = t>>4, nbb = (t&15)*4;
  int tx = t&15, ty = t>>4;
  float acc[4][4];
  #pragma unroll
  for (int i2=0;i2<4;i2++){ acc[i2][0]=0.f; acc[i2][1]=0.f; acc[i2][2]=0.f; acc[i2][3]=0.f; }

  int ael, atp; float asgn_base;
  if (region==0){ ael = am; atp = 0; asgn_base = 1.f; }
  else { ael = am>>1; atp = am&1; asgn_base = atp ? 1.f : -1.f; }
  int segbase0 = (region==2) ? 1280 : 256;

  for (int k0=0;k0<K;k0+=16){
    float4 av;
    if (region==0){
      av = *(const float4*)(Pg + (size_t)ael*2304 + k0 + ak);
    } else {
      int ks = k0 + ak;
      int seg = ks>>7, kk = ks&127;
      int tsel = (seg&1) ? (1-atp) : atp;
      float sg = (seg&1) ? asgn_base : 1.f;
      av = *(const float4*)(Pg + (size_t)ael*2304 + segbase0 + seg*256 + tsel*128 + kk);
      av.x *= sg; av.y *= sg; av.z *= sg; av.w *= sg;
    }
    float4 bv;
    int ks2 = k0 + kb;
    if (region==0){
      bv = *(const float4*)(m0w2 + (size_t)(ks2>>7)*49152 + (size_t)(ks2&127)*384 + ncolbase + nbb);
    } else if (region==1){
      const float* base = ((ks2>>7)&1) ? m1w2i : m1w2r;
      bv = *(const float4*)(base + (size_t)(ks2>>8)*32768 + (size_t)(ks2&127)*256 + ncolbase + nbb);
    } else {
      const float* base = ((ks2>>7)&1) ? m2w2i : m2w2r;
      bv = *(const float4*)(base + (size_t)(ks2>>8)*16384 + (size_t)(ks2&127)*128 + ncolbase + nbb);
    }
    As[ak+0][ar]=av.x; As[ak+1][ar]=av.y; As[ak+2][ar]=av.z; As[ak+3][ar]=av.w;
    *(float4*)&Bs[kb][nbb] = bv;
    __syncthreads();
    #pragma unroll
    for (int k=0;k<16;k++){
      float4 a4 = *(const float4*)&As[k][ty*4];
      float4 b4 = *(const float4*)&Bs[k][tx*4];
      acc[0][0]+=a4.x*b4.x; acc[0][1]+=a4.x*b4.y; acc[0][2]+=a4.x*b4.z; acc[0][3]+=a4.x*b4.w;
      acc[1][0]+=a4.y*b4.x; acc[1][1]+=a4.y*b4.y; acc[1][2]+=a4.y*b4.z; acc[1][3]+=a4.y*b4.w;
      acc[2][0]+=a4.z*b4.x; acc[2][1]+=a4.z*b4.y; acc[2][2]+=a4.z*b4.z; acc[2][3]+=a4.z*b4.w;
      acc[3][0]+=a4.w*b4.x; acc[3][1]+=a4.w*b4.y; acc[3][2]+=a4.w*b4.z; acc[3][3]+=a4.w*b4.w;
    }
    __syncthreads();
  }
  #pragma unroll
  for (int i2=0;i2<4;i2++){
    int m = bm + ty*4 + i2;
    int el, tp;
    if (region==0){ el = m; tp = 0; } else { el = m>>1; tp = m&1; }
    int col = ncolbase + tx*4;
    int g = col >> 7, c = col & 127;
    int ch;
    if (region==0)      ch = (g==0) ? 0 : ((g==1) ? 2 : 6);
    else if (region==1) ch = tp ? (g ? 5 : 1) : (g ? 7 : 3);
    else                ch = tp ? 4 : 8;
    float4 v = make_float4(acc[i2][0],acc[i2][1],acc[i2][2],acc[i2][3]);
    *(float4*)&Y[(size_t)(s0 + el)*1152 + ch*128 + c] = v;
  }
}

// ================= grid transform over compacted slots; Y by slot, R by edge =========
__global__ __launch_bounds__(256, 4) void k_grid4s(const float* __restrict__ Y,
    const float* __restrict__ wig, const float* __restrict__ tg, const float* __restrict__ fg,
    const int* __restrict__ list, const int* __restrict__ countp,
    float* __restrict__ R)
{
  const int cnt = *countp;
  const int base = blockIdx.x*2;
  if (base >= cnt) return;
  __shared__ float cf[324*24];
  __shared__ float wl[2*81];
  int tid = threadIdx.x;
  int s2[2], e2[2];
  s2[0] = base;
  s2[1] = (base+1 < cnt) ? base+1 : cnt-1;
  e2[0] = list[s2[0]];
  e2[1] = list[s2[1]];

  for (int idx = tid; idx < 2916; idx += 256){
    int p = idx / 9, i = idx - p*9;
    cf[p*24 + i]      = tg[idx];
    cf[p*24 + 12 + i] = fg[idx];
  }
  for (int i = tid; i < 162; i += 256){
    int eL2 = i / 81, ii = i - eL2*81;
    wl[i] = wig[(size_t)e2[eL2]*81 + ii];
  }
  __syncthreads();

  int eL = tid >> 7, c = tid & 127;
  int slot = s2[eL], e = e2[eL];

  float y[9], z[9];
  #pragma unroll
  for (int i = 0; i < 9; i++){
    y[i] = Y[(size_t)slot*1152 + i*128 + c];
    z[i] = 0.f;
  }

  #pragma unroll 2
  for (int p = 0; p < 324; p++){
    const float* cp = &cf[p*24];
    float4 t0 = *(const float4*)cp;
    float4 t1 = *(const float4*)(cp+4);
    float  t8 = cp[8];
    float gp = t0.x*y[0] + t0.y*y[1] + t0.z*y[2] + t0.w*y[3]
             + t1.x*y[4] + t1.y*y[5] + t1.z*y[6] + t1.w*y[7] + t8*y[8];
    float s = gp * __fdividef(1.0f, 1.0f + __expf(-gp));
    float4 f0 = *(const float4*)(cp+12);
    float4 f1 = *(const float4*)(cp+16);
    float  f8 = cp[20];
    z[0] += f0.x*s; z[1] += f0.y*s; z[2] += f0.z*s; z[3] += f0.w*s;
    z[4] += f1.x*s; z[5] += f1.y*s; z[6] += f1.z*s; z[7] += f1.w*s; z[8] += f8*s;
  }

  const float* wle = &wl[eL*81];
  #pragma unroll
  for (int i2 = 0; i2 < 9; i2++){
    float s = 0.f;
    #pragma unroll
    for (int j = 0; j < 9; j++) s += wle[j*9 + i2] * z[j];
    R[(size_t)e*1152 + i2*128 + c] = s;
  }
}

// ================= masked reduce + w_out projection (full R, global edge idx) =========
__global__ __launch_bounds__(256) void k_redout2(const float* __restrict__ R,
    const void* __restrict__ maskp, const int* __restrict__ flagp,
    const float* __restrict__ w_out, const float* __restrict__ b_out,
    float* __restrict__ out){
  __shared__ float sacc[128];
  int i2 = blockIdx.x; int n = blockIdx.y;
  int tid = threadIdx.x;
  int f = *flagp;
  if (tid < 128){
    float a = 0.f;
    for (int k = 0; k < 8; k++){
      int e = n*8 + k;
      if (!mask_at(maskp, f, e)) a += R[(size_t)e*1152 + i2*128 + tid];
    }
    sacc[tid] = a;
  }
  __syncthreads();
  int o = tid;
  int deg = d_DEG[i2];
  const float* wp = w_out + (size_t)deg*32768 + o;
  float s = (i2==0) ? b_out[o] : 0.f;
  #pragma unroll 4
  for (int c = 0; c < 128; c += 4){
    float4 a = *(const float4*)&sacc[c];
    s += a.x*wp[(size_t)c*256] + a.y*wp[(size_t)(c+1)*256]
       + a.z*wp[(size_t)(c+2)*256] + a.w*wp[(size_t)(c+3)*256];
  }
  out[((size_t)n*9 + i2)*256 + o] = s;
}

// ================= fallback mega kernel (round-5, pass-verified) =================
__device__ __forceinline__ float dotW(const float* __restrict__ A, const float* __restrict__ Wm, int K){
  float s = 0.f;
  #pragma unroll 4
  for (int i=0;i<K;i+=4){
    float4 a = *(const float4*)&A[i];
    s += a.x*Wm[(size_t)i*128] + a.y*Wm[(size_t)(i+1)*128]
       + a.z*Wm[(size_t)(i+2)*128] + a.w*Wm[(size_t)(i+3)*128];
  }
  return s;
}
__device__ __forceinline__ float dot2W(const float* __restrict__ P0, const float* __restrict__ P1,
    const float* __restrict__ W0, const float* __restrict__ W1, int ldw){
  float s = 0.f;
  #pragma unroll 4
  for (int k=0;k<128;k+=4){
    float4 a = *(const float4*)&P0[k];
    float4 b = *(const float4*)&P1[k];
    s += a.x*W0[(size_t)k*ldw] + a.y*W0[(size_t)(k+1)*ldw] + a.z*W0[(size_t)(k+2)*ldw] + a.w*W0[(size_t)(k+3)*ldw];
    s += b.x*W1[(size_t)k*ldw] + b.y*W1[(size_t)(k+1)*ldw] + b.z*W1[(size_t)(k+2)*ldw] + b.w*W1[(size_t)(k+3)*ldw];
  }
  return s;
}

__global__ __launch_bounds__(256) void k_mega(
    const float* __restrict__ x,      const float* __restrict__ w_in,  const float* __restrict__ b_in,
    const float* __restrict__ attn,
    const float* __restrict__ fdw,    const float* __restrict__ fdb,
    const float* __restrict__ few,    const float* __restrict__ feb,
    const float* __restrict__ es,     const float* __restrict__ et,
    const int*   __restrict__ an,     const int*   __restrict__ esrc,
    const float* __restrict__ d0w,    const float* __restrict__ d0b,
    const float* __restrict__ m1dw,   const float* __restrict__ m1db,
    const float* __restrict__ m2dw,   const float* __restrict__ m2db,
    const float* __restrict__ m0w1,   const float* __restrict__ m0w2,
    const float* __restrict__ m1w1r,  const float* __restrict__ m1w2r,
    const float* __restrict__ m1w1i,  const float* __restrict__ m1w2i,
    const float* __restrict__ m2w1r,  const float* __restrict__ m2w2r,
    const float* __restrict__ m2w1i,  const float* __restrict__ m2w2i,
    const float* __restrict__ wig,    const float* __restrict__ tg,   const float* __restrict__ fg,
    const float* __restrict__ w_out,  const float* __restrict__ b_out,
    const void*  __restrict__ maskp,  const int* __restrict__ flagp,
    float* __restrict__ out)
{
  __shared__ float S[7168];
  float* acc  = S;
  float* xs   = S + 1152;
  float* xtl  = S + 2304;
  float* Zb   = S + 1152;
  float* gg   = S + 3456;
  float* Yb   = S + 3456;
  float* P    = S + 4736;
  float* wl   = S + 7040;
  float* xe16 = S + 7124;
  float* xv   = S + 7140;

  const int n   = blockIdx.x;
  const int tid = threadIdx.x;
  const int f   = *flagp;

  for (int i = tid; i < 1152; i += 256) acc[i] = 0.f;

  for (int k = 0; k < 8; k++){
    int e = n*8 + k;
    if (mask_at(maskp, f, e)) continue;
    int src = esrc[e];
    __syncthreads();
    for (int i = tid; i < 81; i += 256) wl[i] = wig[(size_t)e*81 + i];
    if (tid < 16){
      int j = tid;
      float s = fdb[j] + es[(size_t)an[src]*16 + j] + et[(size_t)an[n]*16 + j];
      for (int kk = 0; kk < 32; kk++) s += attn[(size_t)e*32 + kk] * fdw[kk*16 + j];
      xv[j] = silu_f(s);
    }
    for (int idx = tid; idx < 2304; idx += 256){
      int which = idx >= 1152;
      int lidx = idx - which*1152;
      int j = lidx >> 7, c = lidx & 127;
      int deg = d_DEG[j];
      const float* wp = w_in + (size_t)deg*32768 + c;
      const float* xp = x + ((size_t)(which ? n : src)*9 + j)*256;
      float s = (j==0) ? b_in[c] : 0.f;
      for (int cc = 0; cc < 256; cc++) s += xp[cc] * wp[cc*128];
      P[idx] = s;
    }
    __syncthreads();
    if (tid < 16){
      int j = tid;
      float s = feb[j];
      for (int kk = 0; kk < 16; kk++) s += xv[kk] * few[kk*16 + j];
      xe16[j] = silu_f(s);
    }
    for (int idx = tid; idx < 1152; idx += 256){
      int p = idx >> 7, c = idx & 127;
      int ch = d_PERM[p];
      float s1 = 0.f, s2 = 0.f;
      #pragma unroll
      for (int j = 0; j < 9; j++){
        float wv = wl[ch*9 + j];
        s1 += wv * P[j*128 + c];
        s2 += wv * P[1152 + j*128 + c];
      }
      xs[idx]  = s1;
      xtl[idx] = s2;
    }
    __syncthreads();
    for (int col = tid; col < 1280; col += 256){
      int b = col / 640, r = col % 640;
      const float* w; float bias; int ldw, c2;
      if (r < 128){       w = d0w  + (size_t)b*2048; c2 = r;     ldw = 128; bias = d0b[b*128 + c2]; }
      else if (r < 384){  w = m1dw + (size_t)b*4096; c2 = r-128; ldw = 256; bias = m1db[b*256 + c2]; }
      else {              w = m2dw + (size_t)b*4096; c2 = r-384; ldw = 256; bias = m2db[b*256 + c2]; }
      float s = bias;
      #pragma unroll
      for (int kk = 0; kk < 16; kk++) s += xe16[kk] * w[kk*ldw + c2];
      gg[col] = silu_f(s);
    }
    __syncthreads();
    for (int o = tid; o < 2304; o += 256){
      float s;
      if (o < 256){
        int path = o >> 7, h = o & 127;
        s = dotW(path ? xtl : xs, m0w1 + (size_t)path*49152 + h, 384);
      } else if (o < 1280){
        int q = (o-256) >> 8; int rem = (o-256) & 255; int t = rem >> 7, h = rem & 127;
        const float* A  = ((q>=2) ? xtl : xs) + 384 + t*256;
        const float* Wm = ((q&1) ? m1w1i : m1w1r) + (size_t)((q>=2)?1:0)*32768 + h;
        s = dotW(A, Wm, 256);
      } else {
        int q = (o-1280) >> 8; int rem = (o-1280) & 255; int t = rem >> 7, h = rem & 127;
        const float* A  = ((q>=2) ? xtl : xs) + 896 + t*128;
        const float* Wm = ((q&1) ? m2w1i : m2w1r) + (size_t)((q>=2)?1:0)*16384 + h;
        s = dotW(A, Wm, 128);
      }
      P[o] = s;
    }
    __syncthreads();
    for (int o = tid; o < 2304; o += 256){
      int h = o & 127, goff;
      if (o < 256) goff = (o >> 7) ? 640 : 0;
      else if (o < 1280){ int q = (o-256) >> 8;  goff = 128 + (q&1)*128 + (q>>1)*640; }
      else              { int q = (o-1280) >> 8; goff = 384 + (q&1)*128 + (q>>1)*640; }
      P[o] *= gg[goff + h];
    }
    __syncthreads();
    for (int o = tid; o < 1152; o += 256){
      float s; int ch, c;
      if (o < 384){
        int g = o >> 7; c = o & 127;
        ch = (g==0) ? 0 : ((g==1) ? 2 : 6);
        const float* w0 = m0w2 + o;
        s = dot2W(P, P+128, w0, w0+49152, 384);
      } else if (o < 896){
        int om = o - 384; int tp = om >> 8; int col = om & 255;
        int g = col >> 7; c = col & 127;
        ch = tp ? (g ? 5 : 1) : (g ? 7 : 3);
        float sgn = tp ? 1.f : -1.f;
        const float* wr = m1w2r + col;
        const float* wi = m1w2i + col;
        s = dot2W(P+256+tp*128,     P+768+tp*128,     wr, wr+32768, 256)
          + sgn * dot2W(P+512+(1-tp)*128, P+1024+(1-tp)*128, wi, wi+32768, 256);
      } else {
        int om = o - 896; int tp = om >> 7; c = om & 127;
        ch = tp ? 4 : 8;
        float sgn = tp ? 1.f : -1.f;
        const float* wr = m2w2r + c;
        const float* wi = m2w2i + c;
        s = dot2W(P+1280+tp*128,     P+1792+tp*128,     wr, wr+16384, 128)
          + sgn * dot2W(P+1536+(1-tp)*128, P+2048+(1-tp)*128, wi, wi+16384, 128);
      }
      Yb[ch*128 + c] = s;
    }
    __syncthreads();
    {
      int half = tid >> 7, c = tid & 127;
      float z[9];
      #pragma unroll
      for (int i = 0; i < 9; i++) z[i] = 0.f;
      float y[9];
      #pragma unroll
      for (int i = 0; i < 9; i++) y[i] = Yb[i*128 + c];
      int p0 = half*162, p1 = p0 + 162;
      #pragma unroll 2
      for (int p = p0; p < p1; p++){
        float gp = 0.f;
        #pragma unroll
        for (int i = 0; i < 9; i++) gp += tg[p*9 + i] * y[i];
        float s = silu_f(gp);
        #pragma unroll
        for (int i = 0; i < 9; i++) z[i] += fg[p*9 + i] * s;
      }
      #pragma unroll
      for (int i = 0; i < 9; i++) Zb[half*1152 + i*128 + c] = z[i];
    }
    __syncthreads();
    for (int idx = tid; idx < 1152; idx += 256){
      int i2 = idx >> 7, c = idx & 127;
      float s = 0.f;
      #pragma unroll
      for (int j = 0; j < 9; j++)
        s += wl[j*9 + i2] * (Zb[j*128 + c] + Zb[1152 + j*128 + c]);
      acc[idx] += s;
    }
  }
  __syncthreads();
  {
    int o = tid;
    for (int i2 = 0; i2 < 9; i2++){
      int deg = d_DEG[i2];
      const float* wp = w_out + (size_t)deg*32768 + o;
      float s = (i2==0) ? b_out[o] : 0.f;
      #pragma unroll 4
      for (int c = 0; c < 128; c += 4){
        float4 a = *(const float4*)&acc[i2*128 + c];
        s += a.x*wp[(size_t)c*256] + a.y*wp[(size_t)(c+1)*256]
           + a.z*wp[(size_t)(c+2)*256] + a.w*wp[(size_t)(c+3)*256];
      }
      out[((size_t)n*9 + i2)*256 + o] = s;
    }
  }
}

// ---------------- host ----------------
extern "C" void kernel_launch(void* const* d_in, const int* in_sizes, int n_in,
                              void* d_out, int out_size, void* d_ws, size_t ws_size,
                              hipStream_t stream){
  const float* x     = (const float*)d_in[0];
  const float* attn  = (const float*)d_in[1];
  const float* wig   = (const float*)d_in[2];
  const float* tg    = (const float*)d_in[3];
  const float* fg    = (const float*)d_in[4];
  const float* w_in  = (const float*)d_in[5];
  const float* b_in  = (const float*)d_in[6];
  const float* w_out = (const float*)d_in[7];
  const float* b_out = (const float*)d_in[8];
  const float* es    = (const float*)d_in[9];
  const float* et    = (const float*)d_in[10];
  const float* fdw   = (const float*)d_in[11];
  const float* fdb   = (const float*)d_in[12];
  const float* few   = (const float*)d_in[13];
  const float* feb   = (const float*)d_in[14];
  const float* d0w   = (const float*)d_in[15];
  const float* d0b   = (const float*)d_in[16];
  const float* m0w1  = (const float*)d_in[17];
  const float* m0w2  = (const float*)d_in[18];
  const float* m1dw  = (const float*)d_in[19];
  const float* m1db  = (const float*)d_in[20];
  const float* m1w1r = (const float*)d_in[21];
  const float* m1w2r = (const float*)d_in[22];
  const float* m1w1i = (const float*)d_in[23];
  const float* m1w2i = (const float*)d_in[24];
  const float* m2dw  = (const float*)d_in[25];
  const float* m2db  = (const float*)d_in[26];
  const float* m2w1r = (const float*)d_in[27];
  const float* m2w2r = (const float*)d_in[28];
  const float* m2w1i = (const float*)d_in[29];
  const float* m2w2i = (const float*)d_in[30];
  const int*   an    = (const int*)d_in[31];
  const int*   esrc  = (const int*)d_in[32];
  const void*  maskp = d_in[33];

  int*   ip  = (int*)d_ws;
  int* FLAG  = ip + 0;
  int* COUNT = ip + 1;
  int* LIST  = ip + 16;                 // 4096 ints, ends at float offset 4112
  float* W   = (float*)d_ws;
  float* Hg1  = W + 4112;               // 589824
  float* XEg1 = Hg1 + 589824;           // 65536
  float* XS1  = XEg1 + 65536;           // 2359296 (2048 slots)
  float* XT1  = XS1 + 2359296;          // 2359296
  float* Gg1  = XT1 + 2359296;          // 2621440
  float* Pg1  = Gg1 + 2621440;          // 4718592
  float* Yf   = Pg1 + 4718592;          // 4718592 (4096 slots)
  float* Rf   = XS1;                    // alias XS1+XT1 (4718592) — dead when grid4s runs
  size_t need_t1 = (size_t)(4112 + 589824 + 65536 + 2359296 + 2359296 + 2621440 + 4718592 + 4718592) * 4;

  k_detect<<<1,256,0,stream>>>((const unsigned int*)maskp, FLAG);

  if (ws_size >= need_t1){
    k_compact<<<1,256,0,stream>>>(maskp, FLAG, LIST, COUNT);
    k_h<<<dim3(32,9),128,0,stream>>>(x, w_in, b_in, Hg1);
    k_xe<<<16,256,0,stream>>>(attn, fdw, fdb, few, feb, es, et, an, esrc, XEg1);
    for (int c2 = 0; c2 < 2; c2++){
      int s0 = c2*2048;
      k_rotgate_c<<<2048,256,0,stream>>>(Hg1, XEg1, esrc, wig,
          d0w, d0b, m1dw, m1db, m2dw, m2db, XS1, XT1, Gg1, LIST, COUNT, s0);
      k_gs1<<<1152,256,0,stream>>>(XS1, XT1, Gg1,
          m0w1, m1w1r, m1w1i, m2w1r, m2w1i, Pg1, COUNT, s0);
      k_gs2<<<576,256,0,stream>>>(Pg1, m0w2, m1w2r, m1w2i, m2w2r, m2w2i,
          Yf, COUNT, s0);
    }
    k_grid4s<<<2048,256,0,stream>>>(Yf, wig, tg, fg, LIST, COUNT, Rf);
    k_redout2<<<dim3(9,512),256,0,stream>>>(Rf, maskp, FLAG, w_out, b_out, (float*)d_out);
  } else {
    k_mega<<<512,256,0,stream>>>(
        x, w_in, b_in, attn, fdw, fdb, few, feb, es, et, an, esrc,
        d0w, d0b, m1dw, m1db, m2dw, m2db,
        m0w1, m0w2, m1w1r, m1w2r, m1w1i, m1w2i, m2w1r, m2w2r, m2w1i, m2w2i,
        wig, tg, fg, w_out, b_out, maskp, FLAG, (float*)d_out);
  }
}